// Round 1
// baseline (989.851 us; speedup 1.0000x reference)
//
#include <hip/hip_runtime.h>
#include <math.h>

#define BB 4
#define HH 128
#define WW 128
#define HWP (HH*WW)
#define DIMC 48
#define HIDC 96
#define NSETC 32

// ---------------- K1: attention branch (grouped3x3 -> gate -> 1x1, * gamma + skip 1x1) ----------------
__global__ __launch_bounds__(256) void k_att(
    const float* __restrict__ x,
    const float* __restrict__ c2w1, const float* __restrict__ c2b1,
    const float* __restrict__ c2w2, const float* __restrict__ c2b2,
    const float* __restrict__ c211w, const float* __restrict__ c211b,
    const float* __restrict__ attg,
    float* __restrict__ att, float* __restrict__ pooled)
{
    int tid = threadIdx.x;
    int blk = blockIdx.x;                 // 256 blocks: b*64 + pixel-chunk
    if (blk == 0) {                       // zero pooled accumulator (ws is poisoned)
        for (int i = tid; i < BB * HIDC; i += 256) pooled[i] = 0.f;
    }
    int b = blk >> 6;
    int p = ((blk & 63) << 8) + tid;
    int y = p >> 7, xx = p & 127;
    const float* xb = x + (size_t)b * DIMC * HWP;

    int off[9]; bool ok[9];
    #pragma unroll
    for (int i = 0; i < 3; ++i)
      #pragma unroll
      for (int j = 0; j < 3; ++j) {
        int yy = y + i - 1, xj = xx + j - 1;
        bool o = ((unsigned)yy < (unsigned)HH) & ((unsigned)xj < (unsigned)WW);
        ok[i*3+j] = o;
        off[i*3+j] = o ? (yy * WW + xj) : 0;
      }

    // grouped conv 3x3, groups=24 (2 in-ch per group, 1 out-ch per group)
    float t[24];
    #pragma unroll
    for (int c = 0; c < 24; ++c) {
        float acc = c2b1[c];
        #pragma unroll
        for (int ci = 0; ci < 2; ++ci) {
            const float* xch = xb + (2*c + ci) * HWP;
            const float* w   = c2w1 + (2*c + ci) * 9;
            #pragma unroll
            for (int k = 0; k < 9; ++k) {
                float v = ok[k] ? xch[off[k]] : 0.f;
                acc += w[k] * v;
            }
        }
        t[c] = acc;
    }
    // SimpleGate
    float tg[12];
    #pragma unroll
    for (int k = 0; k < 12; ++k) tg[k] = t[k] * t[k + 12];

    // skip 1x1: 48 -> 32 (streaming)
    float a32[32];
    #pragma unroll
    for (int c = 0; c < 32; ++c) a32[c] = c211b[c];
    for (int k = 0; k < 48; ++k) {
        float xv = xb[k * HWP + p];
        #pragma unroll
        for (int c = 0; c < 32; ++c) a32[c] += c211w[c * 48 + k] * xv;
    }
    // 1x1: 12 -> 32, * gamma + skip
    float* attb = att + (size_t)b * NSETC * HWP;
    #pragma unroll
    for (int c = 0; c < 32; ++c) {
        float v = c2b2[c];
        #pragma unroll
        for (int k = 0; k < 12; ++k) v += c2w2[c * 12 + k] * tg[k];
        attb[c * HWP + p] = v * attg[c] + a32[c];
    }
}

// ---------------- K2: fused 1x1 -> depthwise 3x3, twice (x1 branch, uf branch) ----------------
__global__ __launch_bounds__(256) void k_hidden(
    const float* __restrict__ x,
    const float* __restrict__ dw1w, const float* __restrict__ dw2w,
    const float* __restrict__ c1w1, const float* __restrict__ c1w2,
    float* __restrict__ x1, float* __restrict__ uf)
{
    __shared__ float ys[96][100];          // hidden halo tile (10x10 per 8x8 tile)
    int tid = threadIdx.x;
    int blk = blockIdx.x;                  // 1024: b*256 + ty*16 + tx
    int b = blk >> 8;
    int ty = (blk >> 4) & 15, tx = blk & 15;
    const float* xb = x + (size_t)b * DIMC * HWP;

    // threads 0..99 own one halo position; x[48] in registers
    float xr[48];
    int pos = tid;
    bool act = (pos < 100);
    if (act) {
        int gy = ty*8 - 1 + pos / 10;
        int gx = tx*8 - 1 + pos % 10;
        bool okp = ((unsigned)gy < (unsigned)HH) & ((unsigned)gx < (unsigned)WW);
        int o = okp ? gy * WW + gx : 0;
        #pragma unroll
        for (int k = 0; k < 48; ++k) xr[k] = okp ? xb[k * HWP + o] : 0.f;
    }

    for (int pass = 0; pass < 2; ++pass) {
        const float* wa = pass ? c1w1 : dw1w;
        const float* wd = pass ? c1w2 : dw2w;
        float* outp = pass ? uf : x1;
        if (act) {
            for (int c = 0; c < 96; ++c) {     // c uniform -> scalar weight loads
                const float* wr = wa + c * 48;
                float acc = 0.f;
                #pragma unroll
                for (int k = 0; k < 48; ++k) acc += wr[k] * xr[k];
                ys[c][pos] = acc;
            }
        }
        __syncthreads();
        // depthwise 3x3 on inner 8x8: 96ch * 64px = 6144 outputs
        #pragma unroll 1
        for (int kk = 0; kk < 24; ++kk) {
            int idx = kk * 256 + tid;
            int c = __builtin_amdgcn_readfirstlane(idx >> 6);  // wave-uniform channel
            int l = idx & 63;
            int py = l >> 3, px = l & 7;
            const float* w9 = wd + c * 9;
            float acc = 0.f;
            #pragma unroll
            for (int i = 0; i < 3; ++i)
              #pragma unroll
              for (int j = 0; j < 3; ++j)
                acc += w9[i*3+j] * ys[c][(py+i)*10 + px + j];
            outp[((size_t)b * HIDC + c) * HWP + (ty*8+py) * WW + (tx*8+px)] = acc;
        }
        __syncthreads();   // before ys overwrite in pass 1
    }
}

// ---------------- K3 (hot): KBA + ga1*skip + GELU(x1)*x2 + pooled partial sums ----------------
// grid: 1024 blocks (b,ty,tx); block dim3(64,4): 64 pixels x 4 channel-chunk waves
__global__ __launch_bounds__(256) void k_kba(
    const float* __restrict__ uf, const float* __restrict__ att,
    const float* x1,                      // no restrict: comb aliases x1 (same-thread RAW)
    const float* __restrict__ kbaw, const float* __restrict__ kbab,
    const float* __restrict__ ga1,
    float* comb, float* __restrict__ pooled)
{
    __shared__ float us[96][100];          // uf halo tile  (38.4 KB)
    __shared__ float as[32][64];           // att tile      ( 8.0 KB)
    int lane = threadIdx.x;                // pixel in 8x8 tile
    int wy   = threadIdx.y;                // channel chunk
    int tid  = wy * 64 + lane;
    int blk = blockIdx.x;
    int b = blk >> 8;
    int ty = (blk >> 4) & 15, tx = blk & 15;

    const float* ufb = uf + (size_t)b * HIDC * HWP;
    for (int idx = tid; idx < 96 * 100; idx += 256) {
        int ch = idx / 100, pp = idx % 100;
        int gy = ty*8 - 1 + pp / 10, gx = tx*8 - 1 + pp % 10;
        us[ch][pp] = (((unsigned)gy < (unsigned)HH) & ((unsigned)gx < (unsigned)WW))
                     ? ufb[ch * HWP + gy * WW + gx] : 0.f;
    }
    const float* attb = att + (size_t)b * NSETC * HWP;
    for (int idx = tid; idx < 32 * 64; idx += 256) {
        int n = idx >> 6, l = idx & 63;
        as[n][l] = attb[n * HWP + (ty*8 + (l >> 3)) * WW + tx*8 + (l & 7)];
    }
    __syncthreads();

    int q = __builtin_amdgcn_readfirstlane(wy);   // force scalar chunk index
    int py = lane >> 3, px = lane & 7;
    float a[32];
    #pragma unroll
    for (int n = 0; n < 32; ++n) a[n] = as[n][lane];

    const float* x1b  = x1   + (size_t)b * HIDC * HWP;
    float*       cmbb = comb + (size_t)b * HIDC * HWP;
    int gp = (ty*8 + py) * WW + tx*8 + px;
    int pc = (py + 1) * 10 + (px + 1);

    #pragma unroll 1
    for (int gi = 0; gi < 12; ++gi) {
        int g = q * 12 + gi;
        int ch0 = g * 2;
        float u[18];
        #pragma unroll
        for (int ci = 0; ci < 2; ++ci)
          #pragma unroll
          for (int i = 0; i < 3; ++i)
            #pragma unroll
            for (int j = 0; j < 3; ++j)
              u[ci*9 + i*3 + j] = us[ch0 + ci][(py+i)*10 + px + j];

        float acc0 = 0.f, acc1 = 0.f;
        const float* wg = kbaw + ch0 * 18;    // + n*1728
        const float* bg = kbab + ch0;         // + n*96
        #pragma unroll
        for (int n = 0; n < 32; ++n) {        // fully unrolled: a[n] stays in regs
            const float* w = wg + n * 1728;
            float i0 = bg[n * 96];
            float i1 = bg[n * 96 + 1];
            #pragma unroll
            for (int m = 0; m < 18; ++m) {
                i0 += w[m]      * u[m];       // v_fmac v,s,v (scalar weights)
                i1 += w[18 + m] * u[m];
            }
            float an = a[n];
            acc0 += an * i0;
            acc1 += an * i1;
        }
        // epilogue for channels ch0, ch0+1
        #pragma unroll
        for (int o = 0; o < 2; ++o) {
            int c = ch0 + o;
            float kv = o ? acc1 : acc0;
            float x2 = kv * ga1[c] + us[c][pc];
            float xv = x1b[c * HWP + gp];
            float gel = 0.5f * xv * (1.0f + erff(xv * 0.70710678118654752f));
            float cv = gel * x2;
            cmbb[c * HWP + gp] = cv;
            float r = cv;                      // 64-lane tree reduce for pooled sum
            #pragma unroll
            for (int s = 1; s < 64; s <<= 1) r += __shfl_xor(r, s, 64);
            if (lane == 0) atomicAdd(&pooled[b * HIDC + c], r);
        }
    }
}

// ---------------- K3.5: sca vector = sca_b + sca_w @ mean ----------------
__global__ void k_sv(const float* __restrict__ pooled,
                     const float* __restrict__ scaw, const float* __restrict__ scab,
                     float* __restrict__ sv)
{
    int idx = blockIdx.x * blockDim.x + threadIdx.x;
    if (idx < BB * HIDC) {
        int b = idx / HIDC, c = idx % HIDC;
        float acc = scab[c];
        const float* pr = pooled + b * HIDC;
        const float* wr = scaw + c * HIDC;
        const float inv = 1.0f / (float)HWP;
        for (int k = 0; k < HIDC; ++k) acc += wr[k] * (pr[k] * inv);
        sv[idx] = acc;
    }
}

// ---------------- K4: out = proj1x1( comb * sv ) ----------------
__global__ __launch_bounds__(256) void k_final(
    const float* __restrict__ comb, const float* __restrict__ sv,
    const float* __restrict__ projw, float* __restrict__ out)
{
    int tid = threadIdx.x;
    int blk = blockIdx.x;                 // 256
    int b = blk >> 6;
    int p = ((blk & 63) << 8) + tid;
    const float* cb  = comb + (size_t)b * HIDC * HWP;
    const float* svb = sv + b * HIDC;
    float acc[48];
    #pragma unroll
    for (int o = 0; o < 48; ++o) acc[o] = 0.f;
    for (int c = 0; c < 96; ++c) {        // c uniform -> scalar sv/proj loads
        float v = cb[c * HWP + p] * svb[c];
        #pragma unroll
        for (int o = 0; o < 48; ++o) acc[o] += projw[o * 96 + c] * v;
    }
    float* ob = out + (size_t)b * DIMC * HWP;
    #pragma unroll
    for (int o = 0; o < 48; ++o) ob[o * HWP + p] = acc[o];
}

extern "C" void kernel_launch(void* const* d_in, const int* in_sizes, int n_in,
                              void* d_out, int out_size, void* d_ws, size_t ws_size,
                              hipStream_t stream)
{
    const float* x     = (const float*)d_in[0];
    const float* dw1w  = (const float*)d_in[1];
    const float* dw2w  = (const float*)d_in[2];
    const float* projw = (const float*)d_in[3];
    const float* scaw  = (const float*)d_in[4];
    const float* scab  = (const float*)d_in[5];
    const float* c1w1  = (const float*)d_in[6];
    const float* c1w2  = (const float*)d_in[7];
    const float* kbaw  = (const float*)d_in[8];
    const float* kbab  = (const float*)d_in[9];
    const float* c2w1  = (const float*)d_in[10];
    const float* c2b1  = (const float*)d_in[11];
    const float* c2w2  = (const float*)d_in[12];
    const float* c2b2  = (const float*)d_in[13];
    const float* c211w = (const float*)d_in[14];
    const float* c211b = (const float*)d_in[15];
    const float* attg  = (const float*)d_in[16];
    const float* ga1   = (const float*)d_in[17];

    float* ws = (float*)d_ws;
    float* att    = ws;                                    // 2,097,152 floats
    float* x1     = att + (size_t)BB * NSETC * HWP;        // 6,291,456 floats
    float* uf     = x1  + (size_t)BB * HIDC * HWP;         // 6,291,456 floats
    float* pooled = uf  + (size_t)BB * HIDC * HWP;         // 384
    float* sv     = pooled + BB * HIDC;                    // 384
    float* comb   = x1;   // alias: k_kba reads x1[c,p] then writes comb[c,p] in the same thread

    k_att   <<<256,  256, 0, stream>>>(x, c2w1, c2b1, c2w2, c2b2, c211w, c211b, attg, att, pooled);
    k_hidden<<<1024, 256, 0, stream>>>(x, dw1w, dw2w, c1w1, c1w2, x1, uf);
    k_kba   <<<1024, dim3(64,4,1), 0, stream>>>(uf, att, x1, kbaw, kbab, ga1, comb, pooled);
    k_sv    <<<1,    384, 0, stream>>>(pooled, scaw, scab, sv);
    k_final <<<256,  256, 0, stream>>>(comb, sv, projw, (float*)d_out);
}

// Round 2
// 683.012 us; speedup vs baseline: 1.4492x; 1.4492x over previous
//
#include <hip/hip_runtime.h>
#include <math.h>

#define BB 4
#define HH 128
#define WW 128
#define HWP (HH*WW)
#define DIMC 48
#define HIDC 96
#define NSETC 32

typedef __attribute__((ext_vector_type(8))) short bf16x8;
typedef __attribute__((ext_vector_type(4))) float f32x4;

static __device__ __forceinline__ unsigned short f2bf(float f) {
    union { float f; unsigned u; } v; v.f = f;
    unsigned r = (v.u + 0x7FFFu + ((v.u >> 16) & 1u)) >> 16;
    return (unsigned short)r;
}

// ---------------- K0: pack kbaw/kbab into bf16 MFMA B-fragment order ----------------
// Bpack[ntile(120)][lane(64)][slot(8 halves)] ; col = ntile*16 + (lane&15),
// n = (lane>>4)*8 + slot.  col -> (c = col/20, t = col%20): t<18 weight, t==18 bias, t==19 pad.
__global__ __launch_bounds__(256) void k_pack(
    const float* __restrict__ kbaw, const float* __restrict__ kbab,
    unsigned short* __restrict__ Bp)
{
    int t = blockIdx.x * 256 + threadIdx.x;
    if (t >= 120 * 512) return;
    int ntile = t >> 9;
    int r = t & 511;
    int lane = r >> 3, j = r & 7;
    int n = ((lane >> 4) << 3) + j;
    int col = (ntile << 4) + (lane & 15);
    int c = col / 20, tt = col % 20;
    float v = 0.f;
    if (tt < 18)       v = kbaw[n * 1728 + (c >> 1) * 36 + (c & 1) * 18 + tt];
    else if (tt == 18) v = kbab[n * 96 + c];
    Bp[t] = f2bf(v);
}

// ---------------- K1: attention branch (grouped3x3 -> gate -> 1x1, * gamma + skip 1x1) ----------------
__global__ __launch_bounds__(256) void k_att(
    const float* __restrict__ x,
    const float* __restrict__ c2w1, const float* __restrict__ c2b1,
    const float* __restrict__ c2w2, const float* __restrict__ c2b2,
    const float* __restrict__ c211w, const float* __restrict__ c211b,
    const float* __restrict__ attg,
    float* __restrict__ att, float* __restrict__ pooled)
{
    int tid = threadIdx.x;
    int blk = blockIdx.x;                 // 256 blocks: b*64 + pixel-chunk
    if (blk == 0) {                       // zero pooled accumulator (ws is poisoned)
        for (int i = tid; i < BB * HIDC; i += 256) pooled[i] = 0.f;
    }
    int b = blk >> 6;
    int p = ((blk & 63) << 8) + tid;
    int y = p >> 7, xx = p & 127;
    const float* xb = x + (size_t)b * DIMC * HWP;

    int off[9]; bool ok[9];
    #pragma unroll
    for (int i = 0; i < 3; ++i)
      #pragma unroll
      for (int j = 0; j < 3; ++j) {
        int yy = y + i - 1, xj = xx + j - 1;
        bool o = ((unsigned)yy < (unsigned)HH) & ((unsigned)xj < (unsigned)WW);
        ok[i*3+j] = o;
        off[i*3+j] = o ? (yy * WW + xj) : 0;
      }

    float t[24];
    #pragma unroll
    for (int c = 0; c < 24; ++c) {
        float acc = c2b1[c];
        #pragma unroll
        for (int ci = 0; ci < 2; ++ci) {
            const float* xch = xb + (2*c + ci) * HWP;
            const float* w   = c2w1 + (2*c + ci) * 9;
            #pragma unroll
            for (int k = 0; k < 9; ++k) {
                float v = ok[k] ? xch[off[k]] : 0.f;
                acc += w[k] * v;
            }
        }
        t[c] = acc;
    }
    float tg[12];
    #pragma unroll
    for (int k = 0; k < 12; ++k) tg[k] = t[k] * t[k + 12];

    float a32[32];
    #pragma unroll
    for (int c = 0; c < 32; ++c) a32[c] = c211b[c];
    for (int k = 0; k < 48; ++k) {
        float xv = xb[k * HWP + p];
        #pragma unroll
        for (int c = 0; c < 32; ++c) a32[c] += c211w[c * 48 + k] * xv;
    }
    float* attb = att + (size_t)b * NSETC * HWP;
    #pragma unroll
    for (int c = 0; c < 32; ++c) {
        float v = c2b2[c];
        #pragma unroll
        for (int k = 0; k < 12; ++k) v += c2w2[c * 12 + k] * tg[k];
        attb[c * HWP + p] = v * attg[c] + a32[c];
    }
}

// ---------------- K2: fused 1x1 -> depthwise 3x3, twice (x1 branch, uf branch) ----------------
__global__ __launch_bounds__(256) void k_hidden(
    const float* __restrict__ x,
    const float* __restrict__ dw1w, const float* __restrict__ dw2w,
    const float* __restrict__ c1w1, const float* __restrict__ c1w2,
    float* __restrict__ x1, float* __restrict__ uf)
{
    __shared__ float ys[96][100];          // hidden halo tile (10x10 per 8x8 tile)
    int tid = threadIdx.x;
    int blk = blockIdx.x;                  // 1024: b*256 + ty*16 + tx
    int b = blk >> 8;
    int ty = (blk >> 4) & 15, tx = blk & 15;
    const float* xb = x + (size_t)b * DIMC * HWP;

    // threads 0..199: pos = t%100, half = t/100 handles 48 channels
    float xr[48];
    int pos = tid % 100;
    int half = tid / 100;
    bool act = (tid < 200);
    if (act) {
        int gy = ty*8 - 1 + pos / 10;
        int gx = tx*8 - 1 + pos % 10;
        bool okp = ((unsigned)gy < (unsigned)HH) & ((unsigned)gx < (unsigned)WW);
        int o = okp ? gy * WW + gx : 0;
        #pragma unroll
        for (int k = 0; k < 48; ++k) xr[k] = okp ? xb[k * HWP + o] : 0.f;
    }

    for (int pass = 0; pass < 2; ++pass) {
        const float* wa = pass ? c1w1 : dw1w;
        const float* wd = pass ? c1w2 : dw2w;
        float* outp = pass ? uf : x1;
        if (act) {
            for (int cc = 0; cc < 48; ++cc) {
                int c = half * 48 + cc;
                const float* wr = wa + c * 48;
                float acc = 0.f;
                #pragma unroll
                for (int k = 0; k < 48; ++k) acc += wr[k] * xr[k];
                ys[c][pos] = acc;
            }
        }
        __syncthreads();
        #pragma unroll 1
        for (int kk = 0; kk < 24; ++kk) {
            int idx = kk * 256 + tid;
            int c = __builtin_amdgcn_readfirstlane(idx >> 6);
            int l = idx & 63;
            int py = l >> 3, px = l & 7;
            const float* w9 = wd + c * 9;
            float acc = 0.f;
            #pragma unroll
            for (int i = 0; i < 3; ++i)
              #pragma unroll
              for (int j = 0; j < 3; ++j)
                acc += w9[i*3+j] * ys[c][(py+i)*10 + px + j];
            outp[((size_t)b * HIDC + c) * HWP + (ty*8+py) * WW + (tx*8+px)] = acc;
        }
        __syncthreads();
    }
}

// ---------------- K3 (hot): KBA via MFMA + ga1*skip + GELU(x1)*x2 + pooled sums ----------------
// block dim3(64,4): 64-pixel (8x8) tile, 4 waves. 12 chunks x 8 channels.
// Per chunk: wave wy computes C[16px x 160col] with 10 MFMAs -> Wc LDS -> fp32 18-dot epilogue.
__global__ __launch_bounds__(256) void k_kba(
    const float* __restrict__ uf, const float* __restrict__ att,
    const float* x1,                      // comb aliases x1 (same-thread RAW)
    const uint4* __restrict__ Bp,
    const float* __restrict__ ga1,
    float* comb, float* __restrict__ pooled)
{
    __shared__ float us[96][100];          // uf halo tile  (38.4 KB)
    __shared__ float Wc[64][164];          // mixed-weight chunk (41.0 KB); stride 164 for banks+align
    int lane = threadIdx.x;
    int wy   = threadIdx.y;
    int tid  = wy * 64 + lane;
    int blk = blockIdx.x;
    int b = blk >> 8;
    int ty = (blk >> 4) & 15, tx = blk & 15;

    const float* ufb = uf + (size_t)b * HIDC * HWP;
    for (int idx = tid; idx < 96 * 100; idx += 256) {
        int ch = idx / 100, pp = idx % 100;
        int gy = ty*8 - 1 + pp / 10, gx = tx*8 - 1 + pp % 10;
        us[ch][pp] = (((unsigned)gy < (unsigned)HH) & ((unsigned)gx < (unsigned)WW))
                     ? ufb[ch * HWP + gy * WW + gx] : 0.f;
    }

    // A fragment: row m = lane&15 -> tile pixel wy*16+m ; slot (q=lane>>4, j) -> n = q*8+j
    int pxl = (wy << 4) + (lane & 15);
    int gyA = ty*8 + (pxl >> 3), gxA = tx*8 + (pxl & 7);
    const float* attb = att + (size_t)b * NSETC * HWP + gyA * WW + gxA;
    int q = lane >> 4;
    bf16x8 afrag;
    #pragma unroll
    for (int j = 0; j < 8; ++j) afrag[j] = (short)f2bf(attb[(q*8 + j) * HWP]);

    __syncthreads();

    int py = lane >> 3, px = lane & 7;
    int gp = (ty*8 + py) * WW + tx*8 + px;
    int pc = (py + 1) * 10 + (px + 1);
    const float* x1b  = x1   + (size_t)b * HIDC * HWP;
    float*       cmbb = comb + (size_t)b * HIDC * HWP;
    int colw = lane & 15;
    int rowbase = (wy << 4) + ((lane >> 4) << 2);

    #pragma unroll 1
    for (int chunk = 0; chunk < 12; ++chunk) {
        // --- MFMA phase: cols [chunk*160, chunk*160+160) ---
        #pragma unroll
        for (int nt = 0; nt < 10; ++nt) {
            uint4 braw = Bp[(size_t)((chunk * 10 + nt) << 6) + lane];
            bf16x8 bfrag = __builtin_bit_cast(bf16x8, braw);
            f32x4 z = {0.f, 0.f, 0.f, 0.f};
            f32x4 cfr = __builtin_amdgcn_mfma_f32_16x16x32_bf16(afrag, bfrag, z, 0, 0, 0);
            #pragma unroll
            for (int r = 0; r < 4; ++r)
                Wc[rowbase + r][(nt << 4) + colw] = cfr[r];
        }
        __syncthreads();

        // --- stage 2: thread (lane=pixel, wy) handles channels g2, g2+1 (one group) ---
        int g2 = chunk * 8 + wy * 2;
        float u[18];
        #pragma unroll
        for (int ci = 0; ci < 2; ++ci)
          #pragma unroll
          for (int i = 0; i < 3; ++i)
            #pragma unroll
            for (int j = 0; j < 3; ++j)
              u[ci*9 + i*3 + j] = us[g2 + ci][(py+i)*10 + px + j];

        #pragma unroll
        for (int o = 0; o < 2; ++o) {
            int c = g2 + o;
            const float4* wp = (const float4*)&Wc[lane][(wy*2 + o) * 20];
            float w[20];
            *(float4*)&w[0]  = wp[0];
            *(float4*)&w[4]  = wp[1];
            *(float4*)&w[8]  = wp[2];
            *(float4*)&w[12] = wp[3];
            *(float4*)&w[16] = wp[4];
            float acc = w[18];                       // bias column
            #pragma unroll
            for (int m = 0; m < 18; ++m) acc += w[m] * u[m];

            float x2 = acc * ga1[c] + us[c][pc];
            float xv = x1b[c * HWP + gp];
            float gel = 0.5f * xv * (1.0f + erff(xv * 0.70710678118654752f));
            float cv = gel * x2;
            cmbb[c * HWP + gp] = cv;
            float rsum = cv;
            #pragma unroll
            for (int s = 1; s < 64; s <<= 1) rsum += __shfl_xor(rsum, s, 64);
            if (lane == 0) atomicAdd(&pooled[b * HIDC + c], rsum);
        }
        __syncthreads();
    }
}

// ---------------- K3.5: sca vector = sca_b + sca_w @ mean ----------------
__global__ void k_sv(const float* __restrict__ pooled,
                     const float* __restrict__ scaw, const float* __restrict__ scab,
                     float* __restrict__ sv)
{
    int idx = blockIdx.x * blockDim.x + threadIdx.x;
    if (idx < BB * HIDC) {
        int b = idx / HIDC, c = idx % HIDC;
        float acc = scab[c];
        const float* pr = pooled + b * HIDC;
        const float* wr = scaw + c * HIDC;
        const float inv = 1.0f / (float)HWP;
        for (int k = 0; k < HIDC; ++k) acc += wr[k] * (pr[k] * inv);
        sv[idx] = acc;
    }
}

// ---------------- K4: out = proj1x1( comb * sv ) ----------------
__global__ __launch_bounds__(256) void k_final(
    const float* __restrict__ comb, const float* __restrict__ sv,
    const float* __restrict__ projw, float* __restrict__ out)
{
    int tid = threadIdx.x;
    int blk = blockIdx.x;                 // 256
    int b = blk >> 6;
    int p = ((blk & 63) << 8) + tid;
    const float* cb  = comb + (size_t)b * HIDC * HWP;
    const float* svb = sv + b * HIDC;
    float acc[48];
    #pragma unroll
    for (int o = 0; o < 48; ++o) acc[o] = 0.f;
    for (int c = 0; c < 96; ++c) {
        float v = cb[c * HWP + p] * svb[c];
        #pragma unroll
        for (int o = 0; o < 48; ++o) acc[o] += projw[o * 96 + c] * v;
    }
    float* ob = out + (size_t)b * DIMC * HWP;
    #pragma unroll
    for (int o = 0; o < 48; ++o) ob[o * HWP + p] = acc[o];
}

extern "C" void kernel_launch(void* const* d_in, const int* in_sizes, int n_in,
                              void* d_out, int out_size, void* d_ws, size_t ws_size,
                              hipStream_t stream)
{
    const float* x     = (const float*)d_in[0];
    const float* dw1w  = (const float*)d_in[1];
    const float* dw2w  = (const float*)d_in[2];
    const float* projw = (const float*)d_in[3];
    const float* scaw  = (const float*)d_in[4];
    const float* scab  = (const float*)d_in[5];
    const float* c1w1  = (const float*)d_in[6];
    const float* c1w2  = (const float*)d_in[7];
    const float* kbaw  = (const float*)d_in[8];
    const float* kbab  = (const float*)d_in[9];
    const float* c2w1  = (const float*)d_in[10];
    const float* c2b1  = (const float*)d_in[11];
    const float* c2w2  = (const float*)d_in[12];
    const float* c2b2  = (const float*)d_in[13];
    const float* c211w = (const float*)d_in[14];
    const float* c211b = (const float*)d_in[15];
    const float* attg  = (const float*)d_in[16];
    const float* ga1   = (const float*)d_in[17];

    float* ws = (float*)d_ws;
    float* att    = ws;                                    // 2,097,152 floats
    float* x1     = att + (size_t)BB * NSETC * HWP;        // 6,291,456 floats
    float* uf     = x1  + (size_t)BB * HIDC * HWP;         // 6,291,456 floats
    float* pooled = uf  + (size_t)BB * HIDC * HWP;         // 384
    float* sv     = pooled + BB * HIDC;                    // 384
    unsigned short* Bpack = (unsigned short*)(sv + BB * HIDC);  // 61,440 bf16 (16B-aligned)
    float* comb   = x1;   // alias: k_kba reads x1[c,p] then writes comb[c,p] in the same thread

    k_pack  <<<240,  256, 0, stream>>>(kbaw, kbab, Bpack);
    k_att   <<<256,  256, 0, stream>>>(x, c2w1, c2b1, c2w2, c2b2, c211w, c211b, attg, att, pooled);
    k_hidden<<<1024, 256, 0, stream>>>(x, dw1w, dw2w, c1w1, c1w2, x1, uf);
    k_kba   <<<1024, dim3(64,4,1), 0, stream>>>(uf, att, x1, (const uint4*)Bpack, ga1, comb, pooled);
    k_sv    <<<1,    384, 0, stream>>>(pooled, scaw, scab, sv);
    k_final <<<256,  256, 0, stream>>>(comb, sv, projw, (float*)d_out);
}

// Round 3
// 357.090 us; speedup vs baseline: 2.7720x; 1.9127x over previous
//
#include <hip/hip_runtime.h>
#include <math.h>

#define BB 4
#define HH 128
#define WW 128
#define HWP (HH*WW)
#define DIMC 48
#define HIDC 96
#define NSETC 32

typedef __attribute__((ext_vector_type(8))) short bf16x8;
typedef __attribute__((ext_vector_type(4))) float f32x4;

static __device__ __forceinline__ unsigned short f2bf(float f) {
    union { float f; unsigned u; } v; v.f = f;
    unsigned r = (v.u + 0x7FFFu + ((v.u >> 16) & 1u)) >> 16;
    return (unsigned short)r;
}
static __device__ __forceinline__ float bf2f(unsigned short u) {
    union { unsigned u; float f; } v; v.u = ((unsigned)u) << 16;
    return v.f;
}

// ---------------- K0: pack weights into bf16 MFMA B-fragment order ----------------
// Bp_kba[ntile(120)][lane(64)][slot(8)]: col=ntile*16+(lane&15), n=(lane>>4)*8+slot;
//   col -> (c=col/20, t=col%20): t<18 weight, t==18 bias, t==19 pad.
// Bp_pw[kslice(2)][ntile(12)][lane(64)][slot(8)]: col=out-ch (0..95 dw1, 96..191 c1),
//   k = kslice*32 + (lane>>4)*8 + slot  (k>=48 -> 0).
__global__ __launch_bounds__(256) void k_pack(
    const float* __restrict__ kbaw, const float* __restrict__ kbab,
    const float* __restrict__ dw1w, const float* __restrict__ c1w1,
    unsigned short* __restrict__ Bpk, unsigned short* __restrict__ Bpw)
{
    int t = blockIdx.x * 256 + threadIdx.x;
    if (t < 120 * 512) {
        int ntile = t >> 9;
        int r = t & 511;
        int lane = r >> 3, j = r & 7;
        int n = ((lane >> 4) << 3) + j;
        int col = (ntile << 4) + (lane & 15);
        int c = col / 20, tt = col % 20;
        float v = 0.f;
        if (tt < 18)       v = kbaw[n * 1728 + (c >> 1) * 36 + (c & 1) * 18 + tt];
        else if (tt == 18) v = kbab[n * 96 + c];
        Bpk[t] = f2bf(v);
    } else {
        int u = t - 120 * 512;
        if (u < 2 * 12 * 512) {
            int s = u / 6144;
            int rem = u % 6144;
            int nt = rem >> 9;
            int lane = (rem >> 3) & 63, j = rem & 7;
            int k = s * 32 + ((lane >> 4) << 3) + j;
            int col = (nt << 4) + (lane & 15);
            float v = 0.f;
            if (k < 48) v = (col < 96) ? dw1w[col * 48 + k] : c1w1[(col - 96) * 48 + k];
            Bpw[u] = f2bf(v);
        }
    }
}

// ---------------- K1: attention branch -> att_p[b][p][32] ----------------
__global__ __launch_bounds__(256) void k_att(
    const float* __restrict__ x,
    const float* __restrict__ c2w1, const float* __restrict__ c2b1,
    const float* __restrict__ c2w2, const float* __restrict__ c2b2,
    const float* __restrict__ c211w, const float* __restrict__ c211b,
    const float* __restrict__ attg,
    float* __restrict__ att_p, float* __restrict__ pooled)
{
    int tid = threadIdx.x;
    int blk = blockIdx.x;                 // 256 blocks
    if (blk == 0) {
        for (int i = tid; i < BB * HIDC; i += 256) pooled[i] = 0.f;
    }
    int b = blk >> 6;
    int p = ((blk & 63) << 8) + tid;
    int y = p >> 7, xx = p & 127;
    const float* xb = x + (size_t)b * DIMC * HWP;

    int off[9]; bool ok[9];
    #pragma unroll
    for (int i = 0; i < 3; ++i)
      #pragma unroll
      for (int j = 0; j < 3; ++j) {
        int yy = y + i - 1, xj = xx + j - 1;
        bool o = ((unsigned)yy < (unsigned)HH) & ((unsigned)xj < (unsigned)WW);
        ok[i*3+j] = o;
        off[i*3+j] = o ? (yy * WW + xj) : 0;
      }

    float t[24];
    #pragma unroll
    for (int c = 0; c < 24; ++c) {
        float acc = c2b1[c];
        #pragma unroll
        for (int ci = 0; ci < 2; ++ci) {
            const float* xch = xb + (2*c + ci) * HWP;
            const float* w   = c2w1 + (2*c + ci) * 9;
            #pragma unroll
            for (int k = 0; k < 9; ++k) {
                float v = ok[k] ? xch[off[k]] : 0.f;
                acc += w[k] * v;
            }
        }
        t[c] = acc;
    }
    float tg[12];
    #pragma unroll
    for (int k = 0; k < 12; ++k) tg[k] = t[k] * t[k + 12];

    float a32[32];
    #pragma unroll
    for (int c = 0; c < 32; ++c) a32[c] = c211b[c];
    for (int k = 0; k < 48; ++k) {
        float xv = xb[k * HWP + p];
        #pragma unroll
        for (int c = 0; c < 32; ++c) a32[c] += c211w[c * 48 + k] * xv;
    }
    float v32[32];
    #pragma unroll
    for (int c = 0; c < 32; ++c) {
        float v = c2b2[c];
        #pragma unroll
        for (int k = 0; k < 12; ++k) v += c2w2[c * 12 + k] * tg[k];
        v32[c] = v * attg[c] + a32[c];
    }
    float* ap = att_p + ((size_t)b * HWP + p) * 32;
    #pragma unroll
    for (int c4 = 0; c4 < 8; ++c4)
        *(float4*)&ap[c4 * 4] = *(float4*)&v32[c4 * 4];
}

// ---------------- K2a: both 1x1 convs as bf16 MFMA GEMM -> h_p[b][p][192] bf16 ----------------
__global__ __launch_bounds__(256) void k_pw(
    const float* __restrict__ x, const uint4* __restrict__ Bpw,
    unsigned short* __restrict__ h_p)
{
    int lane = threadIdx.x & 63, w = threadIdx.x >> 6;
    int pbase = blockIdx.x * 256 + w * 64;
    int b = pbase >> 14;
    int prem = pbase & 16383;
    const float* xb = x + (size_t)b * DIMC * HWP;
    int q = lane >> 4, i16 = lane & 15;

    bf16x8 a0[4], a1[4];
    #pragma unroll
    for (int pg = 0; pg < 4; ++pg) {
        int p = prem + pg * 16 + i16;
        #pragma unroll
        for (int j = 0; j < 8; ++j) {
            int k = q * 8 + j;
            a0[pg][j] = (short)f2bf(xb[k * HWP + p]);
        }
        #pragma unroll
        for (int j = 0; j < 8; ++j) {
            int k = 32 + q * 8 + j;
            a1[pg][j] = (k < 48) ? (short)f2bf(xb[k * HWP + p]) : (short)0;
        }
    }
    unsigned short* hb = h_p + (size_t)b * HWP * 192;
    #pragma unroll 1
    for (int nt = 0; nt < 12; ++nt) {
        uint4 b0r = Bpw[(size_t)(nt << 6) + lane];
        uint4 b1r = Bpw[(size_t)((12 + nt) << 6) + lane];
        bf16x8 b0 = __builtin_bit_cast(bf16x8, b0r);
        bf16x8 b1 = __builtin_bit_cast(bf16x8, b1r);
        #pragma unroll
        for (int pg = 0; pg < 4; ++pg) {
            f32x4 z = {0.f, 0.f, 0.f, 0.f};
            f32x4 c = __builtin_amdgcn_mfma_f32_16x16x32_bf16(a1[pg], b1, z, 0, 0, 0);
            c = __builtin_amdgcn_mfma_f32_16x16x32_bf16(a0[pg], b0, c, 0, 0, 0);
            #pragma unroll
            for (int r = 0; r < 4; ++r) {
                int p = prem + pg * 16 + 4 * q + r;
                hb[(size_t)p * 192 + nt * 16 + i16] = f2bf(c[r]);
            }
        }
    }
}

// ---------------- K2b: depthwise 3x3 (both branches) from pixel-major bf16 halo ----------------
__global__ __launch_bounds__(256) void k_dw(
    const unsigned short* __restrict__ h_p,
    const float* __restrict__ dw2w, const float* __restrict__ c1w2,
    float* __restrict__ x1_p, float* __restrict__ uf_p)
{
    __shared__ unsigned short hs[100][200];   // 40 KB
    int tid = threadIdx.x;
    int blk = blockIdx.x;
    int b = blk >> 8, ty = (blk >> 4) & 15, tx = blk & 15;
    const unsigned short* hb = h_p + (size_t)b * HWP * 192;
    for (int idx = tid; idx < 2400; idx += 256) {
        int hp = idx / 24, kk = idx % 24;
        int gy = ty*8 - 1 + hp / 10, gx = tx*8 - 1 + hp % 10;
        uint4 v = {0, 0, 0, 0};
        if (((unsigned)gy < (unsigned)HH) & ((unsigned)gx < (unsigned)WW))
            v = *(const uint4*)&hb[(size_t)(gy * WW + gx) * 192 + kk * 8];
        *(uint4*)&hs[hp][kk * 8] = v;
    }
    __syncthreads();
    #pragma unroll 1
    for (int it = 0; it < 48; ++it) {
        int idx = it * 256 + tid;
        int c = __builtin_amdgcn_readfirstlane(idx >> 6);
        int l = idx & 63;
        int py = l >> 3, px = l & 7;
        const float* w9 = (c < 96) ? &dw2w[c * 9] : &c1w2[(c - 96) * 9];
        float acc = 0.f;
        #pragma unroll
        for (int i = 0; i < 3; ++i)
          #pragma unroll
          for (int j = 0; j < 3; ++j)
            acc += w9[i*3+j] * bf2f(hs[(py+i)*10 + px + j][c]);
        int gp = (ty*8+py) * WW + tx*8+px;
        if (c < 96) x1_p[((size_t)b * HWP + gp) * 96 + c] = acc;
        else        uf_p[((size_t)b * HWP + gp) * 96 + c - 96] = acc;
    }
}

// ---------------- K3 (hot): KBA via MFMA, barrier-free chunk loop ----------------
// block dim3(64,4): wave wy owns pixels wy*16..wy*16+15 for BOTH MFMA rows and epilogue.
__global__ __launch_bounds__(256, 3) void k_kba(
    const float* __restrict__ uf_p, const float* __restrict__ att_p,
    const float* x1_p,                     // comb_p aliases x1_p (same-thread RAW)
    const uint4* __restrict__ Bp, const float* __restrict__ ga1,
    float* comb_p, float* __restrict__ pooled)
{
    __shared__ unsigned short us2[96][101];      // uf halo, bf16 (19.4 KB)
    __shared__ unsigned short Wc[4][16][168];    // wave-private mixed weights, bf16 (21.5 KB)
    __shared__ float pooled_s[96];
    int lane = threadIdx.x, wy = threadIdx.y;
    int tid = wy * 64 + lane;
    int blk = blockIdx.x;
    int b = blk >> 8, ty = (blk >> 4) & 15, tx = blk & 15;
    if (tid < 96) pooled_s[tid] = 0.f;

    const float* ufb = uf_p + (size_t)b * HWP * 96;
    for (int idx = tid; idx < 2400; idx += 256) {
        int hp = idx / 24, cq = idx % 24;
        int gy = ty*8 - 1 + hp / 10, gx = tx*8 - 1 + hp % 10;
        float4 v = {0.f, 0.f, 0.f, 0.f};
        if (((unsigned)gy < (unsigned)HH) & ((unsigned)gx < (unsigned)WW))
            v = *(const float4*)&ufb[(size_t)(gy * WW + gx) * 96 + cq * 4];
        us2[cq*4+0][hp] = f2bf(v.x);
        us2[cq*4+1][hp] = f2bf(v.y);
        us2[cq*4+2][hp] = f2bf(v.z);
        us2[cq*4+3][hp] = f2bf(v.w);
    }

    int q = lane >> 4, i16 = lane & 15;
    int p_t = wy * 16 + i16;                       // this thread's pixel (MFMA row & epilogue)
    int py = p_t >> 3, pxx = p_t & 7;
    int gp = (ty*8 + py) * WW + tx*8 + pxx;
    const float* ab = att_p + ((size_t)b * HWP + gp) * 32;
    float4 av0 = *(const float4*)&ab[q * 8];
    float4 av1 = *(const float4*)&ab[q * 8 + 4];
    bf16x8 afrag;
    afrag[0] = (short)f2bf(av0.x); afrag[1] = (short)f2bf(av0.y);
    afrag[2] = (short)f2bf(av0.z); afrag[3] = (short)f2bf(av0.w);
    afrag[4] = (short)f2bf(av1.x); afrag[5] = (short)f2bf(av1.y);
    afrag[6] = (short)f2bf(av1.z); afrag[7] = (short)f2bf(av1.w);

    __syncthreads();   // the ONLY barrier before the chunk loop

    const float* x1b = x1_p + ((size_t)b * HWP + gp) * 96;
    const float* ufc = ufb + (size_t)gp * 96;
    float* cmb = comb_p + ((size_t)b * HWP + gp) * 96;

    #pragma unroll 1
    for (int chunk = 0; chunk < 12; ++chunk) {
        #pragma unroll
        for (int nt = 0; nt < 10; ++nt) {
            uint4 braw = Bp[(size_t)((chunk * 10 + nt) << 6) + lane];
            bf16x8 bfrag = __builtin_bit_cast(bf16x8, braw);
            f32x4 z = {0.f, 0.f, 0.f, 0.f};
            f32x4 cfr = __builtin_amdgcn_mfma_f32_16x16x32_bf16(afrag, bfrag, z, 0, 0, 0);
            #pragma unroll
            for (int r = 0; r < 4; ++r)
                Wc[wy][4*q + r][nt*16 + i16] = f2bf(cfr[r]);
        }
        // same-wave LDS RAW: no __syncthreads needed (lgkmcnt handles ordering)
        int c0 = chunk * 8 + q * 2;
        float u[18];
        #pragma unroll
        for (int ci = 0; ci < 2; ++ci)
          #pragma unroll
          for (int i = 0; i < 3; ++i)
            #pragma unroll
            for (int j = 0; j < 3; ++j)
              u[ci*9 + i*3 + j] = bf2f(us2[c0 + ci][(py+i)*10 + pxx + j]);

        uint4 wr[5];
        const unsigned short* wrow = &Wc[wy][i16][q * 40];
        #pragma unroll
        for (int t5 = 0; t5 < 5; ++t5) wr[t5] = *(const uint4*)&wrow[t5 * 8];
        const unsigned short* wu = (const unsigned short*)wr;
        float acc0 = bf2f(wu[18]);
        float acc1 = bf2f(wu[38]);
        #pragma unroll
        for (int m = 0; m < 18; ++m) {
            acc0 += bf2f(wu[m])      * u[m];
            acc1 += bf2f(wu[20 + m]) * u[m];
        }
        float2 skip = *(const float2*)&ufc[c0];
        float2 xv   = *(const float2*)&x1b[c0];
        float x20 = acc0 * ga1[c0]     + skip.x;
        float x21 = acc1 * ga1[c0 + 1] + skip.y;
        float gel0 = 0.5f * xv.x * (1.0f + erff(xv.x * 0.70710678118654752f));
        float gel1 = 0.5f * xv.y * (1.0f + erff(xv.y * 0.70710678118654752f));
        float cv0 = gel0 * x20;
        float cv1 = gel1 * x21;
        float2 cvv; cvv.x = cv0; cvv.y = cv1;
        *(float2*)&cmb[c0] = cvv;
        float r0 = cv0, r1 = cv1;
        #pragma unroll
        for (int s = 1; s < 16; s <<= 1) {
            r0 += __shfl_xor(r0, s, 64);
            r1 += __shfl_xor(r1, s, 64);
        }
        if (i16 == 0) {
            atomicAdd(&pooled_s[c0], r0);
            atomicAdd(&pooled_s[c0 + 1], r1);
        }
    }
    __syncthreads();
    if (tid < 96) atomicAdd(&pooled[b * HIDC + tid], pooled_s[tid]);
}

// ---------------- K3.5: sca vector = sca_b + sca_w @ mean ----------------
__global__ void k_sv(const float* __restrict__ pooled,
                     const float* __restrict__ scaw, const float* __restrict__ scab,
                     float* __restrict__ sv)
{
    int idx = blockIdx.x * blockDim.x + threadIdx.x;
    if (idx < BB * HIDC) {
        int b = idx / HIDC, c = idx % HIDC;
        float acc = scab[c];
        const float* pr = pooled + b * HIDC;
        const float* wr = scaw + c * HIDC;
        const float inv = 1.0f / (float)HWP;
        for (int k = 0; k < HIDC; ++k) acc += wr[k] * (pr[k] * inv);
        sv[idx] = acc;
    }
}

// ---------------- K4: out = proj1x1( comb * sv ), comb pixel-major ----------------
__global__ __launch_bounds__(256) void k_final(
    const float* __restrict__ comb_p, const float* __restrict__ sv,
    const float* __restrict__ projw, float* __restrict__ out)
{
    int tid = threadIdx.x;
    int p = blockIdx.x * 256 + tid;
    int b = p >> 14, pl = p & 16383;
    const float* cp = comb_p + (size_t)p * 96;
    const float* svb = sv + b * HIDC;
    float acc[48];
    #pragma unroll
    for (int o = 0; o < 48; ++o) acc[o] = 0.f;
    #pragma unroll 1
    for (int k4 = 0; k4 < 24; ++k4) {
        float4 cv = *(const float4*)&cp[k4 * 4];
        float v0 = cv.x * svb[k4*4+0];
        float v1 = cv.y * svb[k4*4+1];
        float v2 = cv.z * svb[k4*4+2];
        float v3 = cv.w * svb[k4*4+3];
        #pragma unroll
        for (int o = 0; o < 48; ++o) {
            acc[o] += projw[o * 96 + k4*4+0] * v0;
            acc[o] += projw[o * 96 + k4*4+1] * v1;
            acc[o] += projw[o * 96 + k4*4+2] * v2;
            acc[o] += projw[o * 96 + k4*4+3] * v3;
        }
    }
    float* ob = out + (size_t)b * DIMC * HWP + pl;
    #pragma unroll
    for (int o = 0; o < 48; ++o) ob[o * HWP] = acc[o];
}

extern "C" void kernel_launch(void* const* d_in, const int* in_sizes, int n_in,
                              void* d_out, int out_size, void* d_ws, size_t ws_size,
                              hipStream_t stream)
{
    const float* x     = (const float*)d_in[0];
    const float* dw1w  = (const float*)d_in[1];
    const float* dw2w  = (const float*)d_in[2];
    const float* projw = (const float*)d_in[3];
    const float* scaw  = (const float*)d_in[4];
    const float* scab  = (const float*)d_in[5];
    const float* c1w1  = (const float*)d_in[6];
    const float* c1w2  = (const float*)d_in[7];
    const float* kbaw  = (const float*)d_in[8];
    const float* kbab  = (const float*)d_in[9];
    const float* c2w1  = (const float*)d_in[10];
    const float* c2b1  = (const float*)d_in[11];
    const float* c2w2  = (const float*)d_in[12];
    const float* c2b2  = (const float*)d_in[13];
    const float* c211w = (const float*)d_in[14];
    const float* c211b = (const float*)d_in[15];
    const float* attg  = (const float*)d_in[16];
    const float* ga1   = (const float*)d_in[17];

    float* ws = (float*)d_ws;
    float* att_p  = ws;                                     //  2,097,152 f
    float* x1_p   = att_p + (size_t)BB * HWP * NSETC;       //  6,291,456 f
    float* uf_p   = x1_p  + (size_t)BB * HWP * HIDC;        //  6,291,456 f
    float* pooled = uf_p  + (size_t)BB * HWP * HIDC;        //  384
    float* sv     = pooled + BB * HIDC;                     //  384 (ends 16B-aligned)
    unsigned short* h_p  = (unsigned short*)(sv + BB * HIDC);   // 12,582,912 ush
    unsigned short* Bpk  = h_p + (size_t)BB * HWP * 192;        // 61,440 ush
    unsigned short* Bpw  = Bpk + 120 * 512;                     // 12,288 ush
    float* comb_p = x1_p;   // alias: k_kba reads x1_p[p][c] then writes comb same addr

    k_pack <<<288,  256, 0, stream>>>(kbaw, kbab, dw1w, c1w1, Bpk, Bpw);
    k_att  <<<256,  256, 0, stream>>>(x, c2w1, c2b1, c2w2, c2b2, c211w, c211b, attg, att_p, pooled);
    k_pw   <<<256,  256, 0, stream>>>(x, (const uint4*)Bpw, h_p);
    k_dw   <<<1024, 256, 0, stream>>>(h_p, dw2w, c1w2, x1_p, uf_p);
    k_kba  <<<1024, dim3(64,4,1), 0, stream>>>(uf_p, att_p, x1_p, (const uint4*)Bpk, ga1, comb_p, pooled);
    k_sv   <<<1,    384, 0, stream>>>(pooled, scaw, scab, sv);
    k_final<<<256,  256, 0, stream>>>(comb_p, sv, projw, (float*)d_out);
}

// Round 4
// 355.216 us; speedup vs baseline: 2.7866x; 1.0053x over previous
//
#include <hip/hip_runtime.h>
#include <math.h>

#define BB 4
#define HH 128
#define WW 128
#define HWP (HH*WW)
#define DIMC 48
#define HIDC 96
#define NSETC 32

typedef __attribute__((ext_vector_type(8))) short bf16x8;
typedef __attribute__((ext_vector_type(4))) float f32x4;

static __device__ __forceinline__ unsigned short f2bf(float f) {
    union { float f; unsigned u; } v; v.f = f;
    unsigned r = (v.u + 0x7FFFu + ((v.u >> 16) & 1u)) >> 16;
    return (unsigned short)r;
}
static __device__ __forceinline__ float bf2f(unsigned short u) {
    union { unsigned u; float f; } v; v.u = ((unsigned)u) << 16;
    return v.f;
}
static __device__ __forceinline__ float bfpair_lo(unsigned pr) {
    union { unsigned u; float f; } v; v.u = pr << 16; return v.f;
}
static __device__ __forceinline__ float bfpair_hi(unsigned pr) {
    union { unsigned u; float f; } v; v.u = pr & 0xffff0000u; return v.f;
}

// ---------------- K0: pack weights into bf16 MFMA B-fragment order ----------------
__global__ __launch_bounds__(256) void k_pack(
    const float* __restrict__ kbaw, const float* __restrict__ kbab,
    const float* __restrict__ dw1w, const float* __restrict__ c1w1,
    unsigned short* __restrict__ Bpk, unsigned short* __restrict__ Bpw)
{
    int t = blockIdx.x * 256 + threadIdx.x;
    if (t < 120 * 512) {
        int ntile = t >> 9;
        int r = t & 511;
        int lane = r >> 3, j = r & 7;
        int n = ((lane >> 4) << 3) + j;
        int col = (ntile << 4) + (lane & 15);
        int c = col / 20, tt = col % 20;
        float v = 0.f;
        if (tt < 18)       v = kbaw[n * 1728 + (c >> 1) * 36 + (c & 1) * 18 + tt];
        else if (tt == 18) v = kbab[n * 96 + c];
        Bpk[t] = f2bf(v);
    } else {
        int u = t - 120 * 512;
        if (u < 2 * 12 * 512) {
            int s = u / 6144;
            int rem = u % 6144;
            int nt = rem >> 9;
            int lane = (rem >> 3) & 63, j = rem & 7;
            int k = s * 32 + ((lane >> 4) << 3) + j;
            int col = (nt << 4) + (lane & 15);
            float v = 0.f;
            if (k < 48) v = (col < 96) ? dw1w[col * 48 + k] : c1w1[(col - 96) * 48 + k];
            Bpw[u] = f2bf(v);
        }
    }
}

// ---------------- K1: attention branch -> att_p[b][p][32] ----------------
__global__ __launch_bounds__(256) void k_att(
    const float* __restrict__ x,
    const float* __restrict__ c2w1, const float* __restrict__ c2b1,
    const float* __restrict__ c2w2, const float* __restrict__ c2b2,
    const float* __restrict__ c211w, const float* __restrict__ c211b,
    const float* __restrict__ attg,
    float* __restrict__ att_p, float* __restrict__ pooled)
{
    int tid = threadIdx.x;
    int blk = blockIdx.x;
    if (blk == 0) {
        for (int i = tid; i < BB * HIDC; i += 256) pooled[i] = 0.f;
    }
    int b = blk >> 6;
    int p = ((blk & 63) << 8) + tid;
    int y = p >> 7, xx = p & 127;
    const float* xb = x + (size_t)b * DIMC * HWP;

    int off[9]; bool ok[9];
    #pragma unroll
    for (int i = 0; i < 3; ++i)
      #pragma unroll
      for (int j = 0; j < 3; ++j) {
        int yy = y + i - 1, xj = xx + j - 1;
        bool o = ((unsigned)yy < (unsigned)HH) & ((unsigned)xj < (unsigned)WW);
        ok[i*3+j] = o;
        off[i*3+j] = o ? (yy * WW + xj) : 0;
      }

    float t[24];
    #pragma unroll
    for (int c = 0; c < 24; ++c) {
        float acc = c2b1[c];
        #pragma unroll
        for (int ci = 0; ci < 2; ++ci) {
            const float* xch = xb + (2*c + ci) * HWP;
            const float* w   = c2w1 + (2*c + ci) * 9;
            #pragma unroll
            for (int k = 0; k < 9; ++k) {
                float v = ok[k] ? xch[off[k]] : 0.f;
                acc += w[k] * v;
            }
        }
        t[c] = acc;
    }
    float tg[12];
    #pragma unroll
    for (int k = 0; k < 12; ++k) tg[k] = t[k] * t[k + 12];

    float a32[32];
    #pragma unroll
    for (int c = 0; c < 32; ++c) a32[c] = c211b[c];
    for (int k = 0; k < 48; ++k) {
        float xv = xb[k * HWP + p];
        #pragma unroll
        for (int c = 0; c < 32; ++c) a32[c] += c211w[c * 48 + k] * xv;
    }
    float v32[32];
    #pragma unroll
    for (int c = 0; c < 32; ++c) {
        float v = c2b2[c];
        #pragma unroll
        for (int k = 0; k < 12; ++k) v += c2w2[c * 12 + k] * tg[k];
        v32[c] = v * attg[c] + a32[c];
    }
    float* ap = att_p + ((size_t)b * HWP + p) * 32;
    #pragma unroll
    for (int c4 = 0; c4 < 8; ++c4)
        *(float4*)&ap[c4 * 4] = *(float4*)&v32[c4 * 4];
}

// ---------------- K2a: both 1x1 convs as bf16 MFMA GEMM -> h_p[b][p][192] bf16 ----------------
// 512 blocks x 4 waves x 32 px
__global__ __launch_bounds__(256) void k_pw(
    const float* __restrict__ x, const uint4* __restrict__ Bpw,
    unsigned short* __restrict__ h_p)
{
    int lane = threadIdx.x & 63, w = threadIdx.x >> 6;
    int pbase = blockIdx.x * 128 + w * 32;
    int b = pbase >> 14;
    int prem = pbase & 16383;
    const float* xb = x + (size_t)b * DIMC * HWP;
    int q = lane >> 4, i16 = lane & 15;

    bf16x8 a0[2], a1[2];
    #pragma unroll
    for (int pg = 0; pg < 2; ++pg) {
        int p = prem + pg * 16 + i16;
        #pragma unroll
        for (int j = 0; j < 8; ++j) {
            int k = q * 8 + j;
            a0[pg][j] = (short)f2bf(xb[k * HWP + p]);
        }
        #pragma unroll
        for (int j = 0; j < 8; ++j) {
            int k = 32 + q * 8 + j;
            a1[pg][j] = (k < 48) ? (short)f2bf(xb[k * HWP + p]) : (short)0;
        }
    }
    unsigned short* hb = h_p + (size_t)b * HWP * 192;
    #pragma unroll 1
    for (int nt = 0; nt < 12; ++nt) {
        uint4 b0r = Bpw[(size_t)(nt << 6) + lane];
        uint4 b1r = Bpw[(size_t)((12 + nt) << 6) + lane];
        bf16x8 b0 = __builtin_bit_cast(bf16x8, b0r);
        bf16x8 b1 = __builtin_bit_cast(bf16x8, b1r);
        #pragma unroll
        for (int pg = 0; pg < 2; ++pg) {
            f32x4 z = {0.f, 0.f, 0.f, 0.f};
            f32x4 c = __builtin_amdgcn_mfma_f32_16x16x32_bf16(a1[pg], b1, z, 0, 0, 0);
            c = __builtin_amdgcn_mfma_f32_16x16x32_bf16(a0[pg], b0, c, 0, 0, 0);
            #pragma unroll
            for (int r = 0; r < 4; ++r) {
                int p = prem + pg * 16 + 4 * q + r;
                hb[(size_t)p * 192 + nt * 16 + i16] = f2bf(c[r]);
            }
        }
    }
}

// ---------------- K2b: depthwise 3x3, thread = (pixel, channel-quarter) ----------------
__global__ __launch_bounds__(256) void k_dw(
    const unsigned short* __restrict__ h_p,
    const float* __restrict__ dw2w, const float* __restrict__ c1w2,
    float* __restrict__ x1_p, float* __restrict__ uf_p)
{
    __shared__ unsigned short hs[100][200];   // 40 KB; stride 100 dwords -> b128 reads bank-optimal
    int tid = threadIdx.x;
    int blk = blockIdx.x;
    int b = blk >> 8, ty = (blk >> 4) & 15, tx = blk & 15;
    const unsigned short* hb = h_p + (size_t)b * HWP * 192;
    for (int idx = tid; idx < 2400; idx += 256) {
        int hp = idx / 24, kk = idx % 24;
        int gy = ty*8 - 1 + hp / 10, gx = tx*8 - 1 + hp % 10;
        uint4 v = {0, 0, 0, 0};
        if (((unsigned)gy < (unsigned)HH) & ((unsigned)gx < (unsigned)WW))
            v = *(const uint4*)&hb[(size_t)(gy * WW + gx) * 192 + kk * 8];
        *(uint4*)&hs[hp][kk * 8] = v;
    }
    __syncthreads();

    int l = tid & 63;
    int w = __builtin_amdgcn_readfirstlane(tid >> 6);   // wave-uniform channel quarter
    int py = l >> 3, px = l & 7;
    int gp = (ty*8 + py) * WW + tx*8 + px;
    float* outp = (w < 2) ? &x1_p[((size_t)b * HWP + gp) * 96 + w * 48]
                          : &uf_p[((size_t)b * HWP + gp) * 96 + (w - 2) * 48];
    const float* wbase = (w < 2) ? &dw2w[w * 48 * 9] : &c1w2[(w - 2) * 48 * 9];

    #pragma unroll 1
    for (int kk = 0; kk < 6; ++kk) {
        uint4 tv[9];
        #pragma unroll
        for (int i = 0; i < 3; ++i)
          #pragma unroll
          for (int j = 0; j < 3; ++j)
            tv[i*3+j] = *(const uint4*)&hs[(py+i)*10 + px + j][w * 48 + kk * 8];
        const float* w9 = wbase + kk * 8 * 9;           // wave-uniform -> s_loads
        float acc[8];
        #pragma unroll
        for (int c = 0; c < 8; ++c) acc[c] = 0.f;
        #pragma unroll
        for (int t = 0; t < 9; ++t) {
            const unsigned short* hv = (const unsigned short*)&tv[t];
            #pragma unroll
            for (int c = 0; c < 8; ++c)
                acc[c] += w9[c * 9 + t] * bf2f(hv[c]);
        }
        *(float4*)&outp[kk * 8]     = *(float4*)&acc[0];
        *(float4*)&outp[kk * 8 + 4] = *(float4*)&acc[4];
    }
}

// ---------------- K3 (hot): KBA via MFMA, barrier-free chunk loop ----------------
__global__ __launch_bounds__(256, 3) void k_kba(
    const float* __restrict__ uf_p, const float* __restrict__ att_p,
    const float* x1_p,                     // comb_p aliases x1_p (same-thread RAW)
    const uint4* __restrict__ Bp, const float* __restrict__ ga1,
    float* comb_p, float* __restrict__ pooled)
{
    __shared__ unsigned short us2p[100][98];     // uf halo, bf16 pixel-major (19.1 KB); 49-dword stride
    __shared__ unsigned short Wc[4][16][168];    // wave-private mixed weights, bf16 (21.5 KB)
    __shared__ float pooled_s[96];
    int lane = threadIdx.x, wy = threadIdx.y;
    int tid = wy * 64 + lane;
    int blk = blockIdx.x;
    int b = blk >> 8, ty = (blk >> 4) & 15, tx = blk & 15;
    if (tid < 96) pooled_s[tid] = 0.f;

    const float* ufb = uf_p + (size_t)b * HWP * 96;
    for (int idx = tid; idx < 2400; idx += 256) {
        int hp = idx / 24, cq = idx % 24;
        int gy = ty*8 - 1 + hp / 10, gx = tx*8 - 1 + hp % 10;
        float4 v = {0.f, 0.f, 0.f, 0.f};
        if (((unsigned)gy < (unsigned)HH) & ((unsigned)gx < (unsigned)WW))
            v = *(const float4*)&ufb[(size_t)(gy * WW + gx) * 96 + cq * 4];
        unsigned p01 = (unsigned)f2bf(v.x) | ((unsigned)f2bf(v.y) << 16);
        unsigned p23 = (unsigned)f2bf(v.z) | ((unsigned)f2bf(v.w) << 16);
        *(unsigned*)&us2p[hp][cq * 4]     = p01;
        *(unsigned*)&us2p[hp][cq * 4 + 2] = p23;
    }

    int q = lane >> 4, i16 = lane & 15;
    int p_t = wy * 16 + i16;
    int py = p_t >> 3, pxx = p_t & 7;
    int gp = (ty*8 + py) * WW + tx*8 + pxx;
    const float* ab = att_p + ((size_t)b * HWP + gp) * 32;
    float4 av0 = *(const float4*)&ab[q * 8];
    float4 av1 = *(const float4*)&ab[q * 8 + 4];
    bf16x8 afrag;
    afrag[0] = (short)f2bf(av0.x); afrag[1] = (short)f2bf(av0.y);
    afrag[2] = (short)f2bf(av0.z); afrag[3] = (short)f2bf(av0.w);
    afrag[4] = (short)f2bf(av1.x); afrag[5] = (short)f2bf(av1.y);
    afrag[6] = (short)f2bf(av1.z); afrag[7] = (short)f2bf(av1.w);

    __syncthreads();   // the ONLY barrier before the chunk loop

    const float* x1b = x1_p + ((size_t)b * HWP + gp) * 96;
    const float* ufc = ufb + (size_t)gp * 96;
    float* cmb = comb_p + ((size_t)b * HWP + gp) * 96;

    #pragma unroll 1
    for (int chunk = 0; chunk < 12; ++chunk) {
        #pragma unroll
        for (int nt = 0; nt < 10; ++nt) {
            uint4 braw = Bp[(size_t)((chunk * 10 + nt) << 6) + lane];
            bf16x8 bfrag = __builtin_bit_cast(bf16x8, braw);
            f32x4 z = {0.f, 0.f, 0.f, 0.f};
            f32x4 cfr = __builtin_amdgcn_mfma_f32_16x16x32_bf16(afrag, bfrag, z, 0, 0, 0);
            #pragma unroll
            for (int r = 0; r < 4; ++r)
                Wc[wy][4*q + r][nt*16 + i16] = f2bf(cfr[r]);
        }
        // same-wave LDS RAW: lgkmcnt handles ordering, no barrier
        int c0 = chunk * 8 + q * 2;
        float u[18];
        #pragma unroll
        for (int i = 0; i < 3; ++i)
          #pragma unroll
          for (int j = 0; j < 3; ++j) {
              unsigned pr = *(const unsigned*)&us2p[(py+i)*10 + pxx + j][c0];
              u[i*3+j]     = bfpair_lo(pr);
              u[9 + i*3+j] = bfpair_hi(pr);
          }

        uint4 wr[5];
        const unsigned short* wrow = &Wc[wy][i16][q * 40];
        #pragma unroll
        for (int t5 = 0; t5 < 5; ++t5) wr[t5] = *(const uint4*)&wrow[t5 * 8];
        const unsigned short* wu = (const unsigned short*)wr;
        float acc0 = bf2f(wu[18]);
        float acc1 = bf2f(wu[38]);
        #pragma unroll
        for (int m = 0; m < 18; ++m) {
            acc0 += bf2f(wu[m])      * u[m];
            acc1 += bf2f(wu[20 + m]) * u[m];
        }
        float2 skip = *(const float2*)&ufc[c0];
        float2 xv   = *(const float2*)&x1b[c0];
        float x20 = acc0 * ga1[c0]     + skip.x;
        float x21 = acc1 * ga1[c0 + 1] + skip.y;
        float gel0 = 0.5f * xv.x * (1.0f + erff(xv.x * 0.70710678118654752f));
        float gel1 = 0.5f * xv.y * (1.0f + erff(xv.y * 0.70710678118654752f));
        float cv0 = gel0 * x20;
        float cv1 = gel1 * x21;
        float2 cvv; cvv.x = cv0; cvv.y = cv1;
        *(float2*)&cmb[c0] = cvv;
        float r0 = cv0, r1 = cv1;
        #pragma unroll
        for (int s = 1; s < 16; s <<= 1) {
            r0 += __shfl_xor(r0, s, 64);
            r1 += __shfl_xor(r1, s, 64);
        }
        if (i16 == 0) {
            atomicAdd(&pooled_s[c0], r0);
            atomicAdd(&pooled_s[c0 + 1], r1);
        }
    }
    __syncthreads();
    if (tid < 96) atomicAdd(&pooled[b * HIDC + tid], pooled_s[tid]);
}

// ---------------- K3.5: sca vector = sca_b + sca_w @ mean ----------------
__global__ void k_sv(const float* __restrict__ pooled,
                     const float* __restrict__ scaw, const float* __restrict__ scab,
                     float* __restrict__ sv)
{
    int idx = blockIdx.x * blockDim.x + threadIdx.x;
    if (idx < BB * HIDC) {
        int b = idx / HIDC, c = idx % HIDC;
        float acc = scab[c];
        const float* pr = pooled + b * HIDC;
        const float* wr = scaw + c * HIDC;
        const float inv = 1.0f / (float)HWP;
        for (int k = 0; k < HIDC; ++k) acc += wr[k] * (pr[k] * inv);
        sv[idx] = acc;
    }
}

// ---------------- K4: out = proj1x1( comb * sv ), comb pixel-major ----------------
// 512 blocks x 128 threads
__global__ __launch_bounds__(128) void k_final(
    const float* __restrict__ comb_p, const float* __restrict__ sv,
    const float* __restrict__ projw, float* __restrict__ out)
{
    int tid = threadIdx.x;
    int p = blockIdx.x * 128 + tid;
    int b = p >> 14, pl = p & 16383;
    const float* cp = comb_p + (size_t)p * 96;
    const float* svb = sv + b * HIDC;
    float acc[48];
    #pragma unroll
    for (int o = 0; o < 48; ++o) acc[o] = 0.f;
    #pragma unroll 1
    for (int k4 = 0; k4 < 24; ++k4) {
        float4 cv = *(const float4*)&cp[k4 * 4];
        float v0 = cv.x * svb[k4*4+0];
        float v1 = cv.y * svb[k4*4+1];
        float v2 = cv.z * svb[k4*4+2];
        float v3 = cv.w * svb[k4*4+3];
        #pragma unroll
        for (int o = 0; o < 48; ++o) {
            acc[o] += projw[o * 96 + k4*4+0] * v0;
            acc[o] += projw[o * 96 + k4*4+1] * v1;
            acc[o] += projw[o * 96 + k4*4+2] * v2;
            acc[o] += projw[o * 96 + k4*4+3] * v3;
        }
    }
    float* ob = out + (size_t)b * DIMC * HWP + pl;
    #pragma unroll
    for (int o = 0; o < 48; ++o) ob[o * HWP] = acc[o];
}

extern "C" void kernel_launch(void* const* d_in, const int* in_sizes, int n_in,
                              void* d_out, int out_size, void* d_ws, size_t ws_size,
                              hipStream_t stream)
{
    const float* x     = (const float*)d_in[0];
    const float* dw1w  = (const float*)d_in[1];
    const float* dw2w  = (const float*)d_in[2];
    const float* projw = (const float*)d_in[3];
    const float* scaw  = (const float*)d_in[4];
    const float* scab  = (const float*)d_in[5];
    const float* c1w1  = (const float*)d_in[6];
    const float* c1w2  = (const float*)d_in[7];
    const float* kbaw  = (const float*)d_in[8];
    const float* kbab  = (const float*)d_in[9];
    const float* c2w1  = (const float*)d_in[10];
    const float* c2b1  = (const float*)d_in[11];
    const float* c2w2  = (const float*)d_in[12];
    const float* c2b2  = (const float*)d_in[13];
    const float* c211w = (const float*)d_in[14];
    const float* c211b = (const float*)d_in[15];
    const float* attg  = (const float*)d_in[16];
    const float* ga1   = (const float*)d_in[17];

    float* ws = (float*)d_ws;
    float* att_p  = ws;                                     //  2,097,152 f
    float* x1_p   = att_p + (size_t)BB * HWP * NSETC;       //  6,291,456 f
    float* uf_p   = x1_p  + (size_t)BB * HWP * HIDC;        //  6,291,456 f
    float* pooled = uf_p  + (size_t)BB * HWP * HIDC;        //  384
    float* sv     = pooled + BB * HIDC;                     //  384
    unsigned short* h_p  = (unsigned short*)(sv + BB * HIDC);   // 12,582,912 ush
    unsigned short* Bpk  = h_p + (size_t)BB * HWP * 192;        // 61,440 ush
    unsigned short* Bpw  = Bpk + 120 * 512;                     // 12,288 ush
    float* comb_p = x1_p;   // alias: k_kba reads x1_p[p][c] then writes comb same addr

    k_pack <<<288,  256, 0, stream>>>(kbaw, kbab, dw1w, c1w1, Bpk, Bpw);
    k_att  <<<256,  256, 0, stream>>>(x, c2w1, c2b1, c2w2, c2b2, c211w, c211b, attg, att_p, pooled);
    k_pw   <<<512,  256, 0, stream>>>(x, (const uint4*)Bpw, h_p);
    k_dw   <<<1024, 256, 0, stream>>>(h_p, dw2w, c1w2, x1_p, uf_p);
    k_kba  <<<1024, dim3(64,4,1), 0, stream>>>(uf_p, att_p, x1_p, (const uint4*)Bpk, ga1, comb_p, pooled);
    k_sv   <<<1,    384, 0, stream>>>(pooled, scaw, scab, sv);
    k_final<<<512,  128, 0, stream>>>(comb_p, sv, projw, (float*)d_out);
}

// Round 5
// 319.754 us; speedup vs baseline: 3.0957x; 1.1109x over previous
//
#include <hip/hip_runtime.h>
#include <math.h>

#define BB 4
#define HH 128
#define WW 128
#define HWP (HH*WW)
#define DIMC 48
#define HIDC 96
#define NSETC 32

typedef __attribute__((ext_vector_type(8))) short bf16x8;
typedef __attribute__((ext_vector_type(4))) float f32x4;

static __device__ __forceinline__ unsigned short f2bf(float f) {
    union { float f; unsigned u; } v; v.f = f;
    unsigned r = (v.u + 0x7FFFu + ((v.u >> 16) & 1u)) >> 16;
    return (unsigned short)r;
}
static __device__ __forceinline__ float bf2f(unsigned short u) {
    union { unsigned u; float f; } v; v.u = ((unsigned)u) << 16;
    return v.f;
}
static __device__ __forceinline__ float bfpair_lo(unsigned pr) {
    union { unsigned u; float f; } v; v.u = pr << 16; return v.f;
}
static __device__ __forceinline__ float bfpair_hi(unsigned pr) {
    union { unsigned u; float f; } v; v.u = pr & 0xffff0000u; return v.f;
}
static __device__ __forceinline__ float gelu(float x) {
    return 0.5f * x * (1.0f + erff(x * 0.70710678118654752f));
}

// ---------------- K0: pack weights into bf16 MFMA B-fragment order ----------------
__global__ __launch_bounds__(256) void k_pack(
    const float* __restrict__ kbaw, const float* __restrict__ kbab,
    const float* __restrict__ dw1w, const float* __restrict__ c1w1,
    unsigned short* __restrict__ Bpk, unsigned short* __restrict__ Bpw)
{
    int t = blockIdx.x * 256 + threadIdx.x;
    if (t < 120 * 512) {
        int ntile = t >> 9;
        int r = t & 511;
        int lane = r >> 3, j = r & 7;
        int n = ((lane >> 4) << 3) + j;
        int col = (ntile << 4) + (lane & 15);
        int c = col / 20, tt = col % 20;
        float v = 0.f;
        if (tt < 18)       v = kbaw[n * 1728 + (c >> 1) * 36 + (c & 1) * 18 + tt];
        else if (tt == 18) v = kbab[n * 96 + c];
        Bpk[t] = f2bf(v);
    } else {
        int u = t - 120 * 512;
        if (u < 2 * 12 * 512) {
            int s = u / 6144;
            int rem = u % 6144;
            int nt = rem >> 9;
            int lane = (rem >> 3) & 63, j = rem & 7;
            int k = s * 32 + ((lane >> 4) << 3) + j;
            int col = (nt << 4) + (lane & 15);
            float v = 0.f;
            if (k < 48) v = (col < 96) ? dw1w[col * 48 + k] : c1w1[(col - 96) * 48 + k];
            Bpw[u] = f2bf(v);
        }
    }
}

// ---------------- K1: attention branch -> att_p[b][p][32] ----------------
__global__ __launch_bounds__(256) void k_att(
    const float* __restrict__ x,
    const float* __restrict__ c2w1, const float* __restrict__ c2b1,
    const float* __restrict__ c2w2, const float* __restrict__ c2b2,
    const float* __restrict__ c211w, const float* __restrict__ c211b,
    const float* __restrict__ attg,
    float* __restrict__ att_p, float* __restrict__ pooled)
{
    int tid = threadIdx.x;
    int blk = blockIdx.x;
    if (blk == 0) {
        for (int i = tid; i < BB * HIDC; i += 256) pooled[i] = 0.f;
    }
    int b = blk >> 6;
    int p = ((blk & 63) << 8) + tid;
    int y = p >> 7, xx = p & 127;
    const float* xb = x + (size_t)b * DIMC * HWP;

    int off[9]; bool ok[9];
    #pragma unroll
    for (int i = 0; i < 3; ++i)
      #pragma unroll
      for (int j = 0; j < 3; ++j) {
        int yy = y + i - 1, xj = xx + j - 1;
        bool o = ((unsigned)yy < (unsigned)HH) & ((unsigned)xj < (unsigned)WW);
        ok[i*3+j] = o;
        off[i*3+j] = o ? (yy * WW + xj) : 0;
      }

    float t[24];
    #pragma unroll
    for (int c = 0; c < 24; ++c) {
        float acc = c2b1[c];
        #pragma unroll
        for (int ci = 0; ci < 2; ++ci) {
            const float* xch = xb + (2*c + ci) * HWP;
            const float* w   = c2w1 + (2*c + ci) * 9;
            #pragma unroll
            for (int k = 0; k < 9; ++k) {
                float v = ok[k] ? xch[off[k]] : 0.f;
                acc += w[k] * v;
            }
        }
        t[c] = acc;
    }
    float tg[12];
    #pragma unroll
    for (int k = 0; k < 12; ++k) tg[k] = t[k] * t[k + 12];

    float a32[32];
    #pragma unroll
    for (int c = 0; c < 32; ++c) a32[c] = c211b[c];
    for (int k = 0; k < 48; ++k) {
        float xv = xb[k * HWP + p];
        #pragma unroll
        for (int c = 0; c < 32; ++c) a32[c] += c211w[c * 48 + k] * xv;
    }
    float v32[32];
    #pragma unroll
    for (int c = 0; c < 32; ++c) {
        float v = c2b2[c];
        #pragma unroll
        for (int k = 0; k < 12; ++k) v += c2w2[c * 12 + k] * tg[k];
        v32[c] = v * attg[c] + a32[c];
    }
    float* ap = att_p + ((size_t)b * HWP + p) * 32;
    #pragma unroll
    for (int c4 = 0; c4 < 8; ++c4)
        *(float4*)&ap[c4 * 4] = *(float4*)&v32[c4 * 4];
}

// ---------------- K2 (mega-fused): 1x1 MFMA -> depthwise -> KBA -> comb ----------------
// 1024 blocks, dim3(64,4). Per 8x8 tile, everything stays in LDS.
__global__ __launch_bounds__(256, 2) void k_mff(
    const float* __restrict__ x, const float* __restrict__ att_p,
    const uint4* __restrict__ Bpw, const uint4* __restrict__ Bpk,
    const float* __restrict__ c1w2, const float* __restrict__ dw2w,
    const float* __restrict__ ga1,
    float* __restrict__ comb_p, float* __restrict__ pooled)
{
    __shared__ unsigned short bigbuf[144 * 104];     // hs (passes A/B)  ∪  Wc (KBA)  : 29.95 KB
    __shared__ unsigned short us2p[100][104];        // uf 10x10 halo, bf16 pairs     : 20.3 KB
    __shared__ unsigned short gs[64][104];           // gelu(x1) center, bf16         : 13.3 KB
    __shared__ float pooled_s[96];
    unsigned short (*hs)[104] = (unsigned short (*)[104])bigbuf;
    unsigned short (*Wc)[16][168] = (unsigned short (*)[16][168])bigbuf;

    int lane = threadIdx.x, wy = threadIdx.y;
    int tid = wy * 64 + lane;
    int blk = blockIdx.x;
    int b = blk >> 8, ty = (blk >> 4) & 15, tx = blk & 15;
    int q = lane >> 4, i16 = lane & 15;
    if (tid < 96) pooled_s[tid] = 0.f;

    const float* xb = x + (size_t)b * DIMC * HWP;

    // --- att A-fragment (this thread's pixel p_t = wy*16 + i16) ---
    int p_t = wy * 16 + i16;
    int pyT = p_t >> 3, pxT = p_t & 7;
    int gp = (ty*8 + pyT) * WW + tx*8 + pxT;
    const float* ab = att_p + ((size_t)b * HWP + gp) * 32;
    float4 av0 = *(const float4*)&ab[q * 8];
    float4 av1 = *(const float4*)&ab[q * 8 + 4];
    bf16x8 afrag;
    afrag[0] = (short)f2bf(av0.x); afrag[1] = (short)f2bf(av0.y);
    afrag[2] = (short)f2bf(av0.z); afrag[3] = (short)f2bf(av0.w);
    afrag[4] = (short)f2bf(av1.x); afrag[5] = (short)f2bf(av1.y);
    afrag[6] = (short)f2bf(av1.z); afrag[7] = (short)f2bf(av1.w);

    // ================= PASS A: h(c1) on 12x12 halo via MFMA =================
    {
        int rgA[3]; int nA;
        if (wy == 0) { rgA[0] = 0; rgA[1] = 4; rgA[2] = 8; nA = 3; }
        else         { rgA[0] = wy; rgA[1] = wy + 4; rgA[2] = 0; nA = 2; }
        #pragma unroll 1
        for (int rr = 0; rr < nA; ++rr) {
            int rg = rgA[rr];
            int hp = rg * 16 + i16;
            int hy = hp / 12, hx = hp - hy * 12;
            int gy = ty*8 - 2 + hy, gx = tx*8 - 2 + hx;
            bool inb = ((unsigned)gy < (unsigned)HH) & ((unsigned)gx < (unsigned)WW);
            const float* xp = xb + (inb ? gy * WW + gx : 0);
            bf16x8 a0, a1;
            #pragma unroll
            for (int j = 0; j < 8; ++j)
                a0[j] = inb ? (short)f2bf(xp[(q*8 + j) * HWP]) : (short)0;
            #pragma unroll
            for (int j = 0; j < 8; ++j) {
                int k = 32 + q*8 + j;
                a1[j] = (inb && k < 48) ? (short)f2bf(xp[k * HWP]) : (short)0;
            }
            int rowb = rg * 16 + 4 * q;
            #pragma unroll
            for (int nt = 0; nt < 6; ++nt) {
                uint4 b0r = Bpw[(size_t)((6 + nt) << 6) + lane];
                uint4 b1r = Bpw[(size_t)((18 + nt) << 6) + lane];
                bf16x8 b0 = __builtin_bit_cast(bf16x8, b0r);
                bf16x8 b1 = __builtin_bit_cast(bf16x8, b1r);
                f32x4 z = {0.f, 0.f, 0.f, 0.f};
                f32x4 c = __builtin_amdgcn_mfma_f32_16x16x32_bf16(a1, b1, z, 0, 0, 0);
                c = __builtin_amdgcn_mfma_f32_16x16x32_bf16(a0, b0, c, 0, 0, 0);
                #pragma unroll
                for (int r = 0; r < 4; ++r)
                    hs[rowb + r][nt * 16 + i16] = f2bf(c[r]);
            }
        }
    }
    __syncthreads();

    // --- depthwise c1 -> uf on 10x10 halo (us2p, bf16) ---
    #pragma unroll 1
    for (int ci = 0; ci < 3; ++ci) {
        int cq = wy * 3 + ci;                        // channel octet 0..11
        const float* w9 = c1w2 + cq * 8 * 9;         // wave-uniform
        #pragma unroll 1
        for (int sub = 0; sub < 2; ++sub) {
            int hp2 = sub * 64 + lane;
            if (hp2 < 100) {
                int py2 = hp2 / 10, px2 = hp2 - py2 * 10;
                float acc[8];
                #pragma unroll
                for (int c = 0; c < 8; ++c) acc[c] = 0.f;
                #pragma unroll
                for (int di = 0; di < 3; ++di)
                  #pragma unroll
                  for (int dj = 0; dj < 3; ++dj) {
                      uint4 tv = *(const uint4*)&hs[(py2 + di) * 12 + px2 + dj][cq * 8];
                      const unsigned short* hv = (const unsigned short*)&tv;
                      #pragma unroll
                      for (int c = 0; c < 8; ++c)
                          acc[c] += w9[c * 9 + di * 3 + dj] * bf2f(hv[c]);
                  }
                uint4 ov;
                unsigned* op = (unsigned*)&ov;
                #pragma unroll
                for (int c = 0; c < 4; ++c)
                    op[c] = (unsigned)f2bf(acc[2*c]) | ((unsigned)f2bf(acc[2*c+1]) << 16);
                *(uint4*)&us2p[hp2][cq * 8] = ov;
            }
        }
    }
    __syncthreads();

    // ================= PASS B: h(dw) on 10x10 halo via MFMA =================
    {
        int rgB[2]; int nB;
        rgB[0] = wy; rgB[1] = wy + 4; nB = (wy < 3) ? 2 : 1;
        #pragma unroll 1
        for (int rr = 0; rr < nB; ++rr) {
            int rg = rgB[rr];
            int hp = rg * 16 + i16;
            int hy = hp / 10, hx = hp - hy * 10;
            int gy = ty*8 - 1 + hy, gx = tx*8 - 1 + hx;
            bool inb = (hp < 100) & ((unsigned)gy < (unsigned)HH) & ((unsigned)gx < (unsigned)WW);
            const float* xp = xb + (inb ? gy * WW + gx : 0);
            bf16x8 a0, a1;
            #pragma unroll
            for (int j = 0; j < 8; ++j)
                a0[j] = inb ? (short)f2bf(xp[(q*8 + j) * HWP]) : (short)0;
            #pragma unroll
            for (int j = 0; j < 8; ++j) {
                int k = 32 + q*8 + j;
                a1[j] = (inb && k < 48) ? (short)f2bf(xp[k * HWP]) : (short)0;
            }
            int rowb = rg * 16 + 4 * q;
            #pragma unroll
            for (int nt = 0; nt < 6; ++nt) {
                uint4 b0r = Bpw[(size_t)(nt << 6) + lane];
                uint4 b1r = Bpw[(size_t)((12 + nt) << 6) + lane];
                bf16x8 b0 = __builtin_bit_cast(bf16x8, b0r);
                bf16x8 b1 = __builtin_bit_cast(bf16x8, b1r);
                f32x4 z = {0.f, 0.f, 0.f, 0.f};
                f32x4 c = __builtin_amdgcn_mfma_f32_16x16x32_bf16(a1, b1, z, 0, 0, 0);
                c = __builtin_amdgcn_mfma_f32_16x16x32_bf16(a0, b0, c, 0, 0, 0);
                #pragma unroll
                for (int r = 0; r < 4; ++r)
                    if (rowb + r < 104) hs[rowb + r][nt * 16 + i16] = f2bf(c[r]);
            }
        }
    }
    __syncthreads();

    // --- depthwise dw -> gelu(x1) at center 8x8 (gs, bf16) ---
    {
        int py = lane >> 3, pxx = lane & 7;
        #pragma unroll 1
        for (int ci = 0; ci < 3; ++ci) {
            int cq = wy * 3 + ci;
            const float* w9 = dw2w + cq * 8 * 9;
            float acc[8];
            #pragma unroll
            for (int c = 0; c < 8; ++c) acc[c] = 0.f;
            #pragma unroll
            for (int di = 0; di < 3; ++di)
              #pragma unroll
              for (int dj = 0; dj < 3; ++dj) {
                  uint4 tv = *(const uint4*)&hs[(py + di) * 10 + pxx + dj][cq * 8];
                  const unsigned short* hv = (const unsigned short*)&tv;
                  #pragma unroll
                  for (int c = 0; c < 8; ++c)
                      acc[c] += w9[c * 9 + di * 3 + dj] * bf2f(hv[c]);
              }
            uint4 ov;
            unsigned* op = (unsigned*)&ov;
            #pragma unroll
            for (int c = 0; c < 4; ++c)
                op[c] = (unsigned)f2bf(gelu(acc[2*c])) | ((unsigned)f2bf(gelu(acc[2*c+1])) << 16);
            *(uint4*)&gs[lane][cq * 8] = ov;
        }
    }
    __syncthreads();   // hs region now free -> Wc

    // ================= KBA chunk loop (barrier-free) =================
    float* cmb = comb_p + ((size_t)b * HWP + gp) * 96;
    int hpC = (pyT + 1) * 10 + pxT + 1;              // center pixel halo index

    #pragma unroll 1
    for (int chunk = 0; chunk < 12; ++chunk) {
        #pragma unroll
        for (int nt = 0; nt < 10; ++nt) {
            uint4 braw = Bpk[(size_t)((chunk * 10 + nt) << 6) + lane];
            bf16x8 bfrag = __builtin_bit_cast(bf16x8, braw);
            f32x4 z = {0.f, 0.f, 0.f, 0.f};
            f32x4 cfr = __builtin_amdgcn_mfma_f32_16x16x32_bf16(afrag, bfrag, z, 0, 0, 0);
            #pragma unroll
            for (int r = 0; r < 4; ++r)
                Wc[wy][4*q + r][nt*16 + i16] = f2bf(cfr[r]);
        }
        // same-wave LDS RAW: lgkmcnt handles ordering, no barrier
        int c0 = chunk * 8 + q * 2;
        float u[18];
        #pragma unroll
        for (int i = 0; i < 3; ++i)
          #pragma unroll
          for (int j = 0; j < 3; ++j) {
              unsigned pr = *(const unsigned*)&us2p[(pyT + i) * 10 + pxT + j][c0];
              u[i*3+j]     = bfpair_lo(pr);
              u[9 + i*3+j] = bfpair_hi(pr);
          }

        uint4 wr[5];
        const unsigned short* wrow = &Wc[wy][i16][q * 40];
        #pragma unroll
        for (int t5 = 0; t5 < 5; ++t5) wr[t5] = *(const uint4*)&wrow[t5 * 8];
        const unsigned short* wu = (const unsigned short*)wr;
        float acc0 = bf2f(wu[18]);
        float acc1 = bf2f(wu[38]);
        #pragma unroll
        for (int m = 0; m < 18; ++m) {
            acc0 += bf2f(wu[m])      * u[m];
            acc1 += bf2f(wu[20 + m]) * u[m];
        }
        unsigned sp = *(const unsigned*)&us2p[hpC][c0];      // uf skip (bf16 pair)
        unsigned gv = *(const unsigned*)&gs[p_t][c0];        // gelu(x1) (bf16 pair)
        float x20 = acc0 * ga1[c0]     + bfpair_lo(sp);
        float x21 = acc1 * ga1[c0 + 1] + bfpair_hi(sp);
        float cv0 = bfpair_lo(gv) * x20;
        float cv1 = bfpair_hi(gv) * x21;
        float2 cvv; cvv.x = cv0; cvv.y = cv1;
        *(float2*)&cmb[c0] = cvv;
        float r0 = cv0, r1 = cv1;
        #pragma unroll
        for (int s = 1; s < 16; s <<= 1) {
            r0 += __shfl_xor(r0, s, 64);
            r1 += __shfl_xor(r1, s, 64);
        }
        if (i16 == 0) {
            atomicAdd(&pooled_s[c0], r0);
            atomicAdd(&pooled_s[c0 + 1], r1);
        }
    }
    __syncthreads();
    if (tid < 96) atomicAdd(&pooled[b * HIDC + tid], pooled_s[tid]);
}

// ---------------- K3: sca vector = sca_b + sca_w @ mean ----------------
__global__ void k_sv(const float* __restrict__ pooled,
                     const float* __restrict__ scaw, const float* __restrict__ scab,
                     float* __restrict__ sv)
{
    int idx = blockIdx.x * blockDim.x + threadIdx.x;
    if (idx < BB * HIDC) {
        int b = idx / HIDC, c = idx % HIDC;
        float acc = scab[c];
        const float* pr = pooled + b * HIDC;
        const float* wr = scaw + c * HIDC;
        const float inv = 1.0f / (float)HWP;
        for (int k = 0; k < HIDC; ++k) acc += wr[k] * (pr[k] * inv);
        sv[idx] = acc;
    }
}

// ---------------- K4: out = proj1x1( comb * sv ), LDS-transposed ----------------
// 1024 blocks x 256 threads, 64 px per block
__global__ __launch_bounds__(256) void k_final(
    const float* __restrict__ comb_p, const float* __restrict__ sv,
    const float* __restrict__ projw, float* __restrict__ out)
{
    __shared__ float cs[96][66];      // transposed comb*sv tile (25.3 KB)
    int tid = threadIdx.x;
    int blk = blockIdx.x;
    int p0 = blk * 64;
    int b = p0 >> 14;
    const float* svb = sv + b * HIDC;
    for (int idx = tid; idx < 64 * 24; idx += 256) {
        int px = idx / 24, cq = idx - px * 24;
        float4 v = *(const float4*)&comb_p[(size_t)(p0 + px) * 96 + cq * 4];
        int k0 = cq * 4;
        cs[k0 + 0][px] = v.x * svb[k0 + 0];
        cs[k0 + 1][px] = v.y * svb[k0 + 1];
        cs[k0 + 2][px] = v.z * svb[k0 + 2];
        cs[k0 + 3][px] = v.w * svb[k0 + 3];
    }
    __syncthreads();
    int l = tid & 63, w = tid >> 6;
    int o0 = w * 12;
    float acc[12];
    #pragma unroll
    for (int o = 0; o < 12; ++o) acc[o] = 0.f;
    #pragma unroll 4
    for (int k = 0; k < 96; ++k) {
        float v = cs[k][l];
        #pragma unroll
        for (int o = 0; o < 12; ++o)
            acc[o] += projw[(o0 + o) * 96 + k] * v;      // wave-uniform -> s_loads
    }
    float* ob = out + (size_t)b * DIMC * HWP + (p0 & 16383) + l;
    #pragma unroll
    for (int o = 0; o < 12; ++o)
        ob[(o0 + o) * HWP] = acc[o];                     // coalesced dword stores
}

extern "C" void kernel_launch(void* const* d_in, const int* in_sizes, int n_in,
                              void* d_out, int out_size, void* d_ws, size_t ws_size,
                              hipStream_t stream)
{
    const float* x     = (const float*)d_in[0];
    const float* dw1w  = (const float*)d_in[1];
    const float* dw2w  = (const float*)d_in[2];
    const float* projw = (const float*)d_in[3];
    const float* scaw  = (const float*)d_in[4];
    const float* scab  = (const float*)d_in[5];
    const float* c1w1  = (const float*)d_in[6];
    const float* c1w2  = (const float*)d_in[7];
    const float* kbaw  = (const float*)d_in[8];
    const float* kbab  = (const float*)d_in[9];
    const float* c2w1  = (const float*)d_in[10];
    const float* c2b1  = (const float*)d_in[11];
    const float* c2w2  = (const float*)d_in[12];
    const float* c2b2  = (const float*)d_in[13];
    const float* c211w = (const float*)d_in[14];
    const float* c211b = (const float*)d_in[15];
    const float* attg  = (const float*)d_in[16];
    const float* ga1   = (const float*)d_in[17];

    float* ws = (float*)d_ws;
    float* att_p  = ws;                                     //  2,097,152 f
    float* comb_p = att_p + (size_t)BB * HWP * NSETC;       //  6,291,456 f
    float* pooled = comb_p + (size_t)BB * HWP * HIDC;       //  384
    float* sv     = pooled + BB * HIDC;                     //  384
    unsigned short* Bpk = (unsigned short*)(sv + BB * HIDC);    // 61,440 ush
    unsigned short* Bpw = Bpk + 120 * 512;                      // 12,288 ush

    k_pack <<<288,  256, 0, stream>>>(kbaw, kbab, dw1w, c1w1, Bpk, Bpw);
    k_att  <<<256,  256, 0, stream>>>(x, c2w1, c2b1, c2w2, c2b2, c211w, c211b, attg, att_p, pooled);
    k_mff  <<<1024, dim3(64,4,1), 0, stream>>>(x, att_p, (const uint4*)Bpw, (const uint4*)Bpk,
                                               c1w2, dw2w, ga1, comb_p, pooled);
    k_sv   <<<1,    384, 0, stream>>>(pooled, scaw, scab, sv);
    k_final<<<1024, 256, 0, stream>>>(comb_p, sv, projw, (float*)d_out);
}

// Round 6
// 274.936 us; speedup vs baseline: 3.6003x; 1.1630x over previous
//
#include <hip/hip_runtime.h>
#include <math.h>

#define BB 4
#define HH 128
#define WW 128
#define HWP (HH*WW)
#define DIMC 48
#define HIDC 96
#define NSETC 32

typedef __attribute__((ext_vector_type(8))) short bf16x8;
typedef __attribute__((ext_vector_type(4))) float f32x4;

static __device__ __forceinline__ unsigned short f2bf(float f) {
    union { float f; unsigned u; } v; v.f = f;
    unsigned r = (v.u + 0x7FFFu + ((v.u >> 16) & 1u)) >> 16;
    return (unsigned short)r;
}
static __device__ __forceinline__ float bf2f(unsigned short u) {
    union { unsigned u; float f; } v; v.u = ((unsigned)u) << 16;
    return v.f;
}
static __device__ __forceinline__ float bfpair_lo(unsigned pr) {
    union { unsigned u; float f; } v; v.u = pr << 16; return v.f;
}
static __device__ __forceinline__ float bfpair_hi(unsigned pr) {
    union { unsigned u; float f; } v; v.u = pr & 0xffff0000u; return v.f;
}
static __device__ __forceinline__ float gelu(float x) {
    return 0.5f * x * (1.0f + erff(x * 0.70710678118654752f));
}

// ---------------- K0: pack weights into bf16 MFMA B-fragment order ----------------
__global__ __launch_bounds__(256) void k_pack(
    const float* __restrict__ kbaw, const float* __restrict__ kbab,
    const float* __restrict__ dw1w, const float* __restrict__ c1w1,
    unsigned short* __restrict__ Bpk, unsigned short* __restrict__ Bpw)
{
    int t = blockIdx.x * 256 + threadIdx.x;
    if (t < 120 * 512) {
        int ntile = t >> 9;
        int r = t & 511;
        int lane = r >> 3, j = r & 7;
        int n = ((lane >> 4) << 3) + j;
        int col = (ntile << 4) + (lane & 15);
        int c = col / 20, tt = col % 20;
        float v = 0.f;
        if (tt < 18)       v = kbaw[n * 1728 + (c >> 1) * 36 + (c & 1) * 18 + tt];
        else if (tt == 18) v = kbab[n * 96 + c];
        Bpk[t] = f2bf(v);
    } else {
        int u = t - 120 * 512;
        if (u < 2 * 12 * 512) {
            int s = u / 6144;
            int rem = u % 6144;
            int nt = rem >> 9;
            int lane = (rem >> 3) & 63, j = rem & 7;
            int k = s * 32 + ((lane >> 4) << 3) + j;
            int col = (nt << 4) + (lane & 15);
            float v = 0.f;
            if (k < 48) v = (col < 96) ? dw1w[col * 48 + k] : c1w1[(col - 96) * 48 + k];
            Bpw[u] = f2bf(v);
        }
    }
}

// ---------------- K0b: x (ch-major fp32) -> x_p (pixel-major bf16 pairs) ----------------
// 512 blocks x 128 threads; 128 px per block. Also zeroes pooled.
__global__ __launch_bounds__(128) void k_xpose(
    const float* __restrict__ x, unsigned* __restrict__ x_p,
    float* __restrict__ pooled)
{
    __shared__ unsigned ts[128 * 26];
    int tid = threadIdx.x;
    int blk = blockIdx.x;
    if (blk == 0) {
        for (int i = tid; i < BB * HIDC; i += 128) pooled[i] = 0.f;
    }
    int b = blk >> 7;
    int p0 = (blk & 127) << 7;
    const float* xb = x + (size_t)b * DIMC * HWP + p0;
    #pragma unroll
    for (int c2 = 0; c2 < 24; ++c2) {
        float lo = xb[(2 * c2) * HWP + tid];
        float hi = xb[(2 * c2 + 1) * HWP + tid];
        ts[tid * 26 + c2] = (unsigned)f2bf(lo) | ((unsigned)f2bf(hi) << 16);
    }
    __syncthreads();
    unsigned* dst = x_p + ((size_t)b * HWP + p0) * 24;
    for (int idx = tid; idx < 128 * 24; idx += 128) {
        int px = idx / 24, j = idx - px * 24;
        dst[px * 24 + j] = ts[px * 26 + j];
    }
}

// ---------------- K1: attention branch (tile-based, from x_p) -> att_bf pairs ----------------
// 512 blocks x 256 thr: 8x16 px tile, 2 threads/px (r = output half)
__global__ __launch_bounds__(256) void k_att(
    const unsigned* __restrict__ x_p,
    const float* __restrict__ c2w1, const float* __restrict__ c2b1,
    const float* __restrict__ c2w2, const float* __restrict__ c2b2,
    const float* __restrict__ c211w, const float* __restrict__ c211b,
    const float* __restrict__ attg,
    unsigned* __restrict__ att_bf)
{
    __shared__ unsigned xs2[180 * 26];      // 10x18 halo x 24 bf16-pairs (18.7 KB)
    int tid = threadIdx.x;
    int blk = blockIdx.x;
    int b = blk >> 7;
    int tile = blk & 127;
    int ty2 = tile >> 3, tx2 = tile & 7;    // 8-row x 16-col tiles
    const unsigned* xpb = x_p + (size_t)b * HWP * 24;

    for (int idx = tid; idx < 180 * 12; idx += 256) {
        int pos = idx / 12, jj = idx - pos * 12;
        int hy = pos / 18, hx = pos - hy * 18;
        int gy = ty2 * 8 - 1 + hy, gx = tx2 * 16 - 1 + hx;
        uint2 v = {0u, 0u};
        if (((unsigned)gy < (unsigned)HH) & ((unsigned)gx < (unsigned)WW))
            v = *(const uint2*)&xpb[(size_t)(gy * WW + gx) * 24 + jj * 2];
        *(uint2*)&xs2[pos * 26 + jj * 2] = v;
    }
    __syncthreads();

    int px = tid & 127;
    int r = __builtin_amdgcn_readfirstlane(tid >> 7);   // wave-uniform output half
    int py = px >> 4, pxx = px & 15;
    int gp = (ty2 * 8 + py) * WW + tx2 * 16 + pxx;
    int cpos = (py + 1) * 18 + pxx + 1;

    // grouped 3x3 conv (groups=24, 2 in-ch each = one bf16 pair)
    float t[24];
    #pragma unroll
    for (int g = 0; g < 24; ++g) {
        float acc = c2b1[g];
        #pragma unroll
        for (int di = 0; di < 3; ++di)
          #pragma unroll
          for (int dj = 0; dj < 3; ++dj) {
              unsigned pr = xs2[((py + di) * 18 + pxx + dj) * 26 + g];
              acc += c2w1[g * 18 + di * 3 + dj] * bfpair_lo(pr)
                   + c2w1[g * 18 + 9 + di * 3 + dj] * bfpair_hi(pr);
          }
        t[g] = acc;
    }
    float tg[12];
    #pragma unroll
    for (int k = 0; k < 12; ++k) tg[k] = t[k] * t[k + 12];

    // skip 1x1 48->16 (this thread's half of 32 outputs)
    float acc[16];
    #pragma unroll
    for (int o = 0; o < 16; ++o) acc[o] = 0.f;
    #pragma unroll 4
    for (int c2p = 0; c2p < 24; ++c2p) {
        unsigned pr = xs2[cpos * 26 + c2p];
        float lo = bfpair_lo(pr), hi = bfpair_hi(pr);
        #pragma unroll
        for (int o = 0; o < 16; ++o)
            acc[o] += c211w[(r * 16 + o) * 48 + 2 * c2p] * lo
                    + c211w[(r * 16 + o) * 48 + 2 * c2p + 1] * hi;
    }
    // 1x1 12->16, * gamma + skip; pack bf16 pairs
    unsigned ow[8];
    #pragma unroll
    for (int j = 0; j < 8; ++j) {
        float v0 = c2b2[(r * 16 + 2 * j)] ;
        float v1 = c2b2[(r * 16 + 2 * j + 1)];
        #pragma unroll
        for (int k = 0; k < 12; ++k) {
            v0 += c2w2[(r * 16 + 2 * j) * 12 + k] * tg[k];
            v1 += c2w2[(r * 16 + 2 * j + 1) * 12 + k] * tg[k];
        }
        float a0 = v0 * attg[r * 16 + 2 * j]     + c211b[r * 16 + 2 * j]     + acc[2 * j];
        float a1 = v1 * attg[r * 16 + 2 * j + 1] + c211b[r * 16 + 2 * j + 1] + acc[2 * j + 1];
        ow[j] = (unsigned)f2bf(a0) | ((unsigned)f2bf(a1) << 16);
    }
    unsigned* ap = att_bf + ((size_t)b * HWP + gp) * 16 + r * 8;
    *(uint4*)&ap[0] = *(uint4*)&ow[0];
    *(uint4*)&ap[4] = *(uint4*)&ow[4];
}

// ---------------- K2 (mega-fused): 1x1 MFMA -> depthwise -> KBA -> comb ----------------
// 1024 blocks, dim3(64,4). Per 8x8 tile; x read from x_p (contiguous 16B frag loads).
__global__ __launch_bounds__(256, 2) void k_mff(
    const unsigned* __restrict__ x_p, const unsigned* __restrict__ att_bf,
    const uint4* __restrict__ Bpw, const uint4* __restrict__ Bpk,
    const float* __restrict__ c1w2, const float* __restrict__ dw2w,
    const float* __restrict__ ga1,
    float* __restrict__ comb_p, float* __restrict__ pooled)
{
    __shared__ __attribute__((aligned(16))) unsigned short hsw[144 * 100]; // hs ∪ Wc (28.8 KB)
    __shared__ unsigned short us2p[100 * 100];                             // uf halo (20.0 KB)
    __shared__ unsigned short gs[64 * 100];                                // gelu(x1) (12.8 KB)
    __shared__ float pooled_s[96];
    unsigned short (*Wc)[16][168] = (unsigned short (*)[16][168])hsw;

    int lane = threadIdx.x, wy = threadIdx.y;
    int tid = wy * 64 + lane;
    int blk = blockIdx.x;
    int b = blk >> 8, ty = (blk >> 4) & 15, tx = blk & 15;
    int q = lane >> 4, i16 = lane & 15;
    if (tid < 96) pooled_s[tid] = 0.f;

    const unsigned* xpb = x_p + (size_t)b * HWP * 24;

    // --- att A-fragment (pixel p_t = wy*16 + i16) ---
    int p_t = wy * 16 + i16;
    int pyT = p_t >> 3, pxT = p_t & 7;
    int gp = (ty * 8 + pyT) * WW + tx * 8 + pxT;
    uint4 ar = *(const uint4*)&att_bf[((size_t)b * HWP + gp) * 16 + q * 4];
    bf16x8 afrag = __builtin_bit_cast(bf16x8, ar);

    uint4 z4 = {0u, 0u, 0u, 0u};

    // ================= PASS A: h(c1) on 12x12 halo via MFMA =================
    {
        int rgA[3]; int nA;
        if (wy == 0) { rgA[0] = 0; rgA[1] = 4; rgA[2] = 8; nA = 3; }
        else         { rgA[0] = wy; rgA[1] = wy + 4; rgA[2] = 0; nA = 2; }
        #pragma unroll 1
        for (int rr = 0; rr < nA; ++rr) {
            int rg = rgA[rr];
            int hp = rg * 16 + i16;
            int hy = hp / 12, hx = hp - hy * 12;
            int gy = ty * 8 - 2 + hy, gx = tx * 8 - 2 + hx;
            bool inb = ((unsigned)gy < (unsigned)HH) & ((unsigned)gx < (unsigned)WW);
            const uint4* xp4 = (const uint4*)&xpb[(size_t)(inb ? gy * WW + gx : 0) * 24];
            uint4 ra = inb ? xp4[q] : z4;
            uint4 rb = (inb && q < 2) ? xp4[4 + q] : z4;
            bf16x8 a0 = __builtin_bit_cast(bf16x8, ra);
            bf16x8 a1 = __builtin_bit_cast(bf16x8, rb);
            int rowb = rg * 16 + 4 * q;
            #pragma unroll
            for (int nt = 0; nt < 6; ++nt) {
                bf16x8 b0 = __builtin_bit_cast(bf16x8, Bpw[(size_t)((6 + nt) << 6) + lane]);
                bf16x8 b1 = __builtin_bit_cast(bf16x8, Bpw[(size_t)((18 + nt) << 6) + lane]);
                f32x4 z = {0.f, 0.f, 0.f, 0.f};
                f32x4 c = __builtin_amdgcn_mfma_f32_16x16x32_bf16(a1, b1, z, 0, 0, 0);
                c = __builtin_amdgcn_mfma_f32_16x16x32_bf16(a0, b0, c, 0, 0, 0);
                #pragma unroll
                for (int r = 0; r < 4; ++r)
                    hsw[(rowb + r) * 100 + nt * 16 + i16] = f2bf(c[r]);
            }
        }
    }
    __syncthreads();

    // --- depthwise c1 -> uf on 10x10 halo (us2p) ---
    #pragma unroll 1
    for (int ci = 0; ci < 3; ++ci) {
        int cq = wy * 3 + ci;
        const float* w9 = c1w2 + cq * 8 * 9;
        #pragma unroll 1
        for (int sub = 0; sub < 2; ++sub) {
            int hp2 = sub * 64 + lane;
            if (hp2 < 100) {
                int py2 = hp2 / 10, px2 = hp2 - py2 * 10;
                float acc[8];
                #pragma unroll
                for (int c = 0; c < 8; ++c) acc[c] = 0.f;
                #pragma unroll
                for (int di = 0; di < 3; ++di)
                  #pragma unroll
                  for (int dj = 0; dj < 3; ++dj) {
                      int row = (py2 + di) * 12 + px2 + dj;
                      uint2 v0 = *(const uint2*)&hsw[row * 100 + cq * 8];
                      uint2 v1 = *(const uint2*)&hsw[row * 100 + cq * 8 + 4];
                      unsigned pp[4] = {v0.x, v0.y, v1.x, v1.y};
                      #pragma unroll
                      for (int c2 = 0; c2 < 4; ++c2) {
                          acc[2*c2]   += w9[(2*c2) * 9 + di * 3 + dj]   * bfpair_lo(pp[c2]);
                          acc[2*c2+1] += w9[(2*c2+1) * 9 + di * 3 + dj] * bfpair_hi(pp[c2]);
                      }
                  }
                uint2 o0, o1;
                o0.x = (unsigned)f2bf(acc[0]) | ((unsigned)f2bf(acc[1]) << 16);
                o0.y = (unsigned)f2bf(acc[2]) | ((unsigned)f2bf(acc[3]) << 16);
                o1.x = (unsigned)f2bf(acc[4]) | ((unsigned)f2bf(acc[5]) << 16);
                o1.y = (unsigned)f2bf(acc[6]) | ((unsigned)f2bf(acc[7]) << 16);
                *(uint2*)&us2p[hp2 * 100 + cq * 8]     = o0;
                *(uint2*)&us2p[hp2 * 100 + cq * 8 + 4] = o1;
            }
        }
    }
    __syncthreads();

    // ================= PASS B: h(dw) on 10x10 halo via MFMA =================
    {
        int rgB[2]; rgB[0] = wy; rgB[1] = wy + 4;
        int nB = (wy < 3) ? 2 : 1;
        #pragma unroll 1
        for (int rr = 0; rr < nB; ++rr) {
            int rg = rgB[rr];
            int hp = rg * 16 + i16;
            bool okp = hp < 100;
            int hy = hp / 10, hx = hp - hy * 10;
            int gy = ty * 8 - 1 + hy, gx = tx * 8 - 1 + hx;
            bool inb = okp & ((unsigned)gy < (unsigned)HH) & ((unsigned)gx < (unsigned)WW);
            const uint4* xp4 = (const uint4*)&xpb[(size_t)(inb ? gy * WW + gx : 0) * 24];
            uint4 ra = inb ? xp4[q] : z4;
            uint4 rb = (inb && q < 2) ? xp4[4 + q] : z4;
            bf16x8 a0 = __builtin_bit_cast(bf16x8, ra);
            bf16x8 a1 = __builtin_bit_cast(bf16x8, rb);
            int rowb = rg * 16 + 4 * q;
            #pragma unroll
            for (int nt = 0; nt < 6; ++nt) {
                bf16x8 b0 = __builtin_bit_cast(bf16x8, Bpw[(size_t)(nt << 6) + lane]);
                bf16x8 b1 = __builtin_bit_cast(bf16x8, Bpw[(size_t)((12 + nt) << 6) + lane]);
                f32x4 z = {0.f, 0.f, 0.f, 0.f};
                f32x4 c = __builtin_amdgcn_mfma_f32_16x16x32_bf16(a1, b1, z, 0, 0, 0);
                c = __builtin_amdgcn_mfma_f32_16x16x32_bf16(a0, b0, c, 0, 0, 0);
                #pragma unroll
                for (int r = 0; r < 4; ++r)
                    hsw[(rowb + r) * 100 + nt * 16 + i16] = f2bf(c[r]);   // rows>=100 harmless
            }
        }
    }
    __syncthreads();

    // --- depthwise dw -> gelu(x1) at center 8x8 (gs) ---
    {
        int py = lane >> 3, pxx = lane & 7;
        #pragma unroll 1
        for (int ci = 0; ci < 3; ++ci) {
            int cq = wy * 3 + ci;
            const float* w9 = dw2w + cq * 8 * 9;
            float acc[8];
            #pragma unroll
            for (int c = 0; c < 8; ++c) acc[c] = 0.f;
            #pragma unroll
            for (int di = 0; di < 3; ++di)
              #pragma unroll
              for (int dj = 0; dj < 3; ++dj) {
                  int row = (py + di) * 10 + pxx + dj;
                  uint2 v0 = *(const uint2*)&hsw[row * 100 + cq * 8];
                  uint2 v1 = *(const uint2*)&hsw[row * 100 + cq * 8 + 4];
                  unsigned pp[4] = {v0.x, v0.y, v1.x, v1.y};
                  #pragma unroll
                  for (int c2 = 0; c2 < 4; ++c2) {
                      acc[2*c2]   += w9[(2*c2) * 9 + di * 3 + dj]   * bfpair_lo(pp[c2]);
                      acc[2*c2+1] += w9[(2*c2+1) * 9 + di * 3 + dj] * bfpair_hi(pp[c2]);
                  }
              }
            uint2 o0, o1;
            o0.x = (unsigned)f2bf(gelu(acc[0])) | ((unsigned)f2bf(gelu(acc[1])) << 16);
            o0.y = (unsigned)f2bf(gelu(acc[2])) | ((unsigned)f2bf(gelu(acc[3])) << 16);
            o1.x = (unsigned)f2bf(gelu(acc[4])) | ((unsigned)f2bf(gelu(acc[5])) << 16);
            o1.y = (unsigned)f2bf(gelu(acc[6])) | ((unsigned)f2bf(gelu(acc[7])) << 16);
            *(uint2*)&gs[lane * 100 + cq * 8]     = o0;
            *(uint2*)&gs[lane * 100 + cq * 8 + 4] = o1;
        }
    }
    __syncthreads();   // hs region now free -> Wc

    // ================= KBA chunk loop (barrier-free) =================
    float* cmb = comb_p + ((size_t)b * HWP + gp) * 96;
    int hpC = (pyT + 1) * 10 + pxT + 1;

    #pragma unroll 1
    for (int chunk = 0; chunk < 12; ++chunk) {
        #pragma unroll
        for (int nt = 0; nt < 10; ++nt) {
            bf16x8 bfrag = __builtin_bit_cast(bf16x8, Bpk[(size_t)((chunk * 10 + nt) << 6) + lane]);
            f32x4 z = {0.f, 0.f, 0.f, 0.f};
            f32x4 cfr = __builtin_amdgcn_mfma_f32_16x16x32_bf16(afrag, bfrag, z, 0, 0, 0);
            #pragma unroll
            for (int r = 0; r < 4; ++r)
                Wc[wy][4 * q + r][nt * 16 + i16] = f2bf(cfr[r]);
        }
        // same-wave LDS RAW: lgkmcnt handles ordering, no barrier
        int c0 = chunk * 8 + q * 2;
        float u[18];
        #pragma unroll
        for (int i = 0; i < 3; ++i)
          #pragma unroll
          for (int j = 0; j < 3; ++j) {
              unsigned pr = *(const unsigned*)&us2p[((pyT + i) * 10 + pxT + j) * 100 + c0];
              u[i * 3 + j]     = bfpair_lo(pr);
              u[9 + i * 3 + j] = bfpair_hi(pr);
          }

        uint4 wr[5];
        const unsigned short* wrow = &Wc[wy][i16][q * 40];
        #pragma unroll
        for (int t5 = 0; t5 < 5; ++t5) wr[t5] = *(const uint4*)&wrow[t5 * 8];
        const unsigned short* wu = (const unsigned short*)wr;
        float acc0 = bf2f(wu[18]);
        float acc1 = bf2f(wu[38]);
        #pragma unroll
        for (int m = 0; m < 18; ++m) {
            acc0 += bf2f(wu[m])      * u[m];
            acc1 += bf2f(wu[20 + m]) * u[m];
        }
        unsigned sp = *(const unsigned*)&us2p[hpC * 100 + c0];
        unsigned gv = *(const unsigned*)&gs[p_t * 100 + c0];
        float x20 = acc0 * ga1[c0]     + bfpair_lo(sp);
        float x21 = acc1 * ga1[c0 + 1] + bfpair_hi(sp);
        float cv0 = bfpair_lo(gv) * x20;
        float cv1 = bfpair_hi(gv) * x21;
        float2 cvv; cvv.x = cv0; cvv.y = cv1;
        *(float2*)&cmb[c0] = cvv;
        float r0 = cv0, r1 = cv1;
        #pragma unroll
        for (int s = 1; s < 16; s <<= 1) {
            r0 += __shfl_xor(r0, s, 64);
            r1 += __shfl_xor(r1, s, 64);
        }
        if (i16 == 0) {
            atomicAdd(&pooled_s[c0], r0);
            atomicAdd(&pooled_s[c0 + 1], r1);
        }
    }
    __syncthreads();
    if (tid < 96) atomicAdd(&pooled[b * HIDC + tid], pooled_s[tid]);
}

// ---------------- K3: sca vector = sca_b + sca_w @ mean ----------------
__global__ void k_sv(const float* __restrict__ pooled,
                     const float* __restrict__ scaw, const float* __restrict__ scab,
                     float* __restrict__ sv)
{
    int idx = blockIdx.x * blockDim.x + threadIdx.x;
    if (idx < BB * HIDC) {
        int b = idx / HIDC, c = idx % HIDC;
        float acc = scab[c];
        const float* pr = pooled + b * HIDC;
        const float* wr = scaw + c * HIDC;
        const float inv = 1.0f / (float)HWP;
        for (int k = 0; k < HIDC; ++k) acc += wr[k] * (pr[k] * inv);
        sv[idx] = acc;
    }
}

// ---------------- K4: out = proj1x1( comb * sv ), LDS-transposed ----------------
__global__ __launch_bounds__(256) void k_final(
    const float* __restrict__ comb_p, const float* __restrict__ sv,
    const float* __restrict__ projw, float* __restrict__ out)
{
    __shared__ float cs[96][66];
    int tid = threadIdx.x;
    int blk = blockIdx.x;
    int p0 = blk * 64;
    int b = p0 >> 14;
    const float* svb = sv + b * HIDC;
    for (int idx = tid; idx < 64 * 24; idx += 256) {
        int px = idx / 24, cq = idx - px * 24;
        float4 v = *(const float4*)&comb_p[(size_t)(p0 + px) * 96 + cq * 4];
        int k0 = cq * 4;
        cs[k0 + 0][px] = v.x * svb[k0 + 0];
        cs[k0 + 1][px] = v.y * svb[k0 + 1];
        cs[k0 + 2][px] = v.z * svb[k0 + 2];
        cs[k0 + 3][px] = v.w * svb[k0 + 3];
    }
    __syncthreads();
    int l = tid & 63, w = tid >> 6;
    int o0 = w * 12;
    float acc[12];
    #pragma unroll
    for (int o = 0; o < 12; ++o) acc[o] = 0.f;
    #pragma unroll 4
    for (int k = 0; k < 96; ++k) {
        float v = cs[k][l];
        #pragma unroll
        for (int o = 0; o < 12; ++o)
            acc[o] += projw[(o0 + o) * 96 + k] * v;
    }
    float* ob = out + (size_t)b * DIMC * HWP + (p0 & 16383) + l;
    #pragma unroll
    for (int o = 0; o < 12; ++o)
        ob[(o0 + o) * HWP] = acc[o];
}

extern "C" void kernel_launch(void* const* d_in, const int* in_sizes, int n_in,
                              void* d_out, int out_size, void* d_ws, size_t ws_size,
                              hipStream_t stream)
{
    const float* x     = (const float*)d_in[0];
    const float* dw1w  = (const float*)d_in[1];
    const float* dw2w  = (const float*)d_in[2];
    const float* projw = (const float*)d_in[3];
    const float* scaw  = (const float*)d_in[4];
    const float* scab  = (const float*)d_in[5];
    const float* c1w1  = (const float*)d_in[6];
    const float* c1w2  = (const float*)d_in[7];
    const float* kbaw  = (const float*)d_in[8];
    const float* kbab  = (const float*)d_in[9];
    const float* c2w1  = (const float*)d_in[10];
    const float* c2b1  = (const float*)d_in[11];
    const float* c2w2  = (const float*)d_in[12];
    const float* c2b2  = (const float*)d_in[13];
    const float* c211w = (const float*)d_in[14];
    const float* c211b = (const float*)d_in[15];
    const float* attg  = (const float*)d_in[16];
    const float* ga1   = (const float*)d_in[17];

    unsigned* x_p    = (unsigned*)d_ws;                          // 1,572,864 dw
    unsigned* att_bf = x_p + (size_t)BB * HWP * 24;              // 1,048,576 dw
    float* comb_p    = (float*)(att_bf + (size_t)BB * HWP * 16); // 6,291,456 f
    float* pooled    = comb_p + (size_t)BB * HWP * 96;           // 384
    float* sv        = pooled + BB * HIDC;                       // 384
    unsigned short* Bpk = (unsigned short*)(sv + BB * HIDC);     // 61,440 ush
    unsigned short* Bpw = Bpk + 120 * 512;                       // 12,288 ush

    k_pack <<<288,  256, 0, stream>>>(kbaw, kbab, dw1w, c1w1, Bpk, Bpw);
    k_xpose<<<512,  128, 0, stream>>>(x, x_p, pooled);
    k_att  <<<512,  256, 0, stream>>>(x_p, c2w1, c2b1, c2w2, c2b2, c211w, c211b, attg, att_bf);
    k_mff  <<<1024, dim3(64,4,1), 0, stream>>>(x_p, att_bf, (const uint4*)Bpw, (const uint4*)Bpk,
                                               c1w2, dw2w, ga1, comb_p, pooled);
    k_sv   <<<1,    384, 0, stream>>>(pooled, scaw, scab, sv);
    k_final<<<1024, 256, 0, stream>>>(comb_p, sv, projw, (float*)d_out);
}

// Round 7
// 245.982 us; speedup vs baseline: 4.0241x; 1.1177x over previous
//
#include <hip/hip_runtime.h>
#include <math.h>

#define BB 4
#define HH 128
#define WW 128
#define HWP (HH*WW)
#define DIMC 48
#define HIDC 96
#define NSETC 32

typedef __attribute__((ext_vector_type(8))) short bf16x8;
typedef __attribute__((ext_vector_type(4))) float f32x4;
typedef __attribute__((ext_vector_type(2))) float f32x2;

static __device__ __forceinline__ unsigned short f2bf(float f) {   // RNE (pack path, cold)
    union { float f; unsigned u; } v; v.f = f;
    unsigned r = (v.u + 0x7FFFu + ((v.u >> 16) & 1u)) >> 16;
    return (unsigned short)r;
}
static __device__ __forceinline__ unsigned rnd_bf(float f) {       // +0x8000 round-half-up
    union { float f; unsigned u; } v; v.f = f;
    return v.u + 0x8000u;
}
static __device__ __forceinline__ unsigned pack2bf(float lo, float hi) {
    return __builtin_amdgcn_perm(rnd_bf(hi), rnd_bf(lo), 0x07060302u);
}
static __device__ __forceinline__ void st_bf_hi(unsigned short* p, float f) {
    *p = (unsigned short)(rnd_bf(f) >> 16);    // -> ds_write_b16_d16_hi
}
static __device__ __forceinline__ float bf2f(unsigned short u) {
    union { unsigned u; float f; } v; v.u = ((unsigned)u) << 16;
    return v.f;
}
static __device__ __forceinline__ float bfpair_lo(unsigned pr) {
    union { unsigned u; float f; } v; v.u = pr << 16; return v.f;
}
static __device__ __forceinline__ float bfpair_hi(unsigned pr) {
    union { unsigned u; float f; } v; v.u = pr & 0xffff0000u; return v.f;
}
static __device__ __forceinline__ float gelu(float x) {
    return 0.5f * x * (1.0f + erff(x * 0.70710678118654752f));
}

// ---------------- K0: weight pack (Bpk channel-remap + ga1 fold) + x transpose ----------------
// blocks [0,288): pack ; blocks [288,544): xpose (256 px each) ; xblk 0 zeroes pooled
__global__ __launch_bounds__(256) void k_prep(
    const float* __restrict__ x,
    const float* __restrict__ kbaw, const float* __restrict__ kbab,
    const float* __restrict__ dw1w, const float* __restrict__ c1w1,
    const float* __restrict__ ga1,
    unsigned short* __restrict__ Bpk, unsigned short* __restrict__ Bpw,
    unsigned* __restrict__ x_p, float* __restrict__ pooled)
{
    __shared__ unsigned ts[256 * 26];
    int blk = blockIdx.x, tid = threadIdx.x;
    if (blk < 288) {
        int t = blk * 256 + tid;
        if (t < 120 * 512) {
            int ntile = t >> 9;
            int r = t & 511;
            int lane = r >> 3, j = r & 7;
            int n = ((lane >> 4) << 3) + j;
            int chunkc = ntile / 10;
            int col = ((ntile % 10) << 4) + (lane & 15);
            int qq = col / 40, rem = col % 40;
            int o = rem / 20, tt = rem % 20;
            int c = qq * 24 + 2 * chunkc + o;          // chunk cc covers channels q*24+2cc+o
            float v = 0.f;
            if (tt < 18)       v = kbaw[n * 1728 + (c >> 1) * 36 + (c & 1) * 18 + tt] * ga1[c];
            else if (tt == 18) v = kbab[n * 96 + c] * ga1[c];
            Bpk[t] = f2bf(v);
        } else {
            int u = t - 120 * 512;
            if (u < 2 * 12 * 512) {
                int s = u / 6144;
                int rem = u % 6144;
                int nt = rem >> 9;
                int lane = (rem >> 3) & 63, j = rem & 7;
                int k = s * 32 + ((lane >> 4) << 3) + j;
                int col = (nt << 4) + (lane & 15);
                float v = 0.f;
                if (k < 48) v = (col < 96) ? dw1w[col * 48 + k] : c1w1[(col - 96) * 48 + k];
                Bpw[u] = f2bf(v);
            }
        }
    } else {
        int xblk = blk - 288;
        if (xblk == 0) {
            for (int i = tid; i < BB * HIDC; i += 256) pooled[i] = 0.f;
        }
        int b = xblk >> 6;
        int p0 = (xblk & 63) << 8;
        const float* xb = x + (size_t)b * DIMC * HWP + p0;
        #pragma unroll
        for (int c2 = 0; c2 < 24; ++c2) {
            float lo = xb[(2 * c2) * HWP + tid];
            float hi = xb[(2 * c2 + 1) * HWP + tid];
            ts[tid * 26 + c2] = pack2bf(lo, hi);
        }
        __syncthreads();
        unsigned* dst = x_p + ((size_t)b * HWP + p0) * 24;
        for (int idx = tid; idx < 256 * 24; idx += 256) {
            int px = idx / 24, j2 = idx - px * 24;
            dst[px * 24 + j2] = ts[px * 26 + j2];
        }
    }
}

// ---------------- K1: attention branch (tile-based, from x_p) -> att_bf pairs ----------------
__global__ __launch_bounds__(256) void k_att(
    const unsigned* __restrict__ x_p,
    const float* __restrict__ c2w1, const float* __restrict__ c2b1,
    const float* __restrict__ c2w2, const float* __restrict__ c2b2,
    const float* __restrict__ c211w, const float* __restrict__ c211b,
    const float* __restrict__ attg,
    unsigned* __restrict__ att_bf)
{
    __shared__ unsigned xs2[180 * 26];
    int tid = threadIdx.x;
    int blk = blockIdx.x;
    int b = blk >> 7;
    int tile = blk & 127;
    int ty2 = tile >> 3, tx2 = tile & 7;
    const unsigned* xpb = x_p + (size_t)b * HWP * 24;

    for (int idx = tid; idx < 180 * 12; idx += 256) {
        int pos = idx / 12, jj = idx - pos * 12;
        int hy = pos / 18, hx = pos - hy * 18;
        int gy = ty2 * 8 - 1 + hy, gx = tx2 * 16 - 1 + hx;
        uint2 v = {0u, 0u};
        if (((unsigned)gy < (unsigned)HH) & ((unsigned)gx < (unsigned)WW))
            v = *(const uint2*)&xpb[(size_t)(gy * WW + gx) * 24 + jj * 2];
        *(uint2*)&xs2[pos * 26 + jj * 2] = v;
    }
    __syncthreads();

    int px = tid & 127;
    int r = __builtin_amdgcn_readfirstlane(tid >> 7);
    int py = px >> 4, pxx = px & 15;
    int gp = (ty2 * 8 + py) * WW + tx2 * 16 + pxx;
    int cpos = (py + 1) * 18 + pxx + 1;

    float t[24];
    #pragma unroll
    for (int g = 0; g < 24; ++g) {
        float acc = c2b1[g];
        #pragma unroll
        for (int di = 0; di < 3; ++di)
          #pragma unroll
          for (int dj = 0; dj < 3; ++dj) {
              unsigned pr = xs2[((py + di) * 18 + pxx + dj) * 26 + g];
              acc += c2w1[g * 18 + di * 3 + dj] * bfpair_lo(pr)
                   + c2w1[g * 18 + 9 + di * 3 + dj] * bfpair_hi(pr);
          }
        t[g] = acc;
    }
    float tg[12];
    #pragma unroll
    for (int k = 0; k < 12; ++k) tg[k] = t[k] * t[k + 12];

    float acc[16];
    #pragma unroll
    for (int o = 0; o < 16; ++o) acc[o] = 0.f;
    #pragma unroll 4
    for (int c2p = 0; c2p < 24; ++c2p) {
        unsigned pr = xs2[cpos * 26 + c2p];
        float lo = bfpair_lo(pr), hi = bfpair_hi(pr);
        #pragma unroll
        for (int o = 0; o < 16; ++o)
            acc[o] += c211w[(r * 16 + o) * 48 + 2 * c2p] * lo
                    + c211w[(r * 16 + o) * 48 + 2 * c2p + 1] * hi;
    }
    unsigned ow[8];
    #pragma unroll
    for (int j = 0; j < 8; ++j) {
        float v0 = c2b2[(r * 16 + 2 * j)];
        float v1 = c2b2[(r * 16 + 2 * j + 1)];
        #pragma unroll
        for (int k = 0; k < 12; ++k) {
            v0 += c2w2[(r * 16 + 2 * j) * 12 + k] * tg[k];
            v1 += c2w2[(r * 16 + 2 * j + 1) * 12 + k] * tg[k];
        }
        float a0 = v0 * attg[r * 16 + 2 * j]     + c211b[r * 16 + 2 * j]     + acc[2 * j];
        float a1 = v1 * attg[r * 16 + 2 * j + 1] + c211b[r * 16 + 2 * j + 1] + acc[2 * j + 1];
        ow[j] = pack2bf(a0, a1);
    }
    unsigned* ap = att_bf + ((size_t)b * HWP + gp) * 16 + r * 8;
    *(uint4*)&ap[0] = *(uint4*)&ow[0];
    *(uint4*)&ap[4] = *(uint4*)&ow[4];
}

// ---------------- K2 (mega-fused): 1x1 MFMA -> depthwise -> KBA -> comb(bf16) ----------------
// 1024 blocks, dim3(64,4); 3 blocks/CU (LDS 51.4 KB)
__global__ __launch_bounds__(256, 3) void k_mff(
    const unsigned* __restrict__ x_p, const unsigned* __restrict__ att_bf,
    const uint4* __restrict__ Bpw, const uint4* __restrict__ Bpk,
    const float* __restrict__ c1w2, const float* __restrict__ dw2w,
    unsigned* __restrict__ comb_bf, float* __restrict__ pooled)
{
    __shared__ __attribute__((aligned(16))) unsigned short hsw[144 * 100];  // h tiles ∪ Wc (28.8 KB)
    __shared__ unsigned short us2p[100 * 100];                              // uf halo (20.0 KB)
    __shared__ float wlds[9 * 96];                                          // dw2w [tap][ch] (3.4 KB)
    __shared__ float pooled_s[96];
    unsigned short (*Wc)[16][168] = (unsigned short (*)[16][168])hsw;

    int lane = threadIdx.x, wy = threadIdx.y;
    int tid = wy * 64 + lane;
    int blk = blockIdx.x;
    int b = blk >> 8, ty = (blk >> 4) & 15, tx = blk & 15;
    int q = lane >> 4, i16 = lane & 15;
    if (tid < 96) pooled_s[tid] = 0.f;
    for (int idx = tid; idx < 864; idx += 256) {
        int t = idx / 96, c = idx - t * 96;
        wlds[idx] = dw2w[c * 9 + t];
    }

    const unsigned* xpb = x_p + (size_t)b * HWP * 24;

    int p_t = wy * 16 + i16;
    int pyT = p_t >> 3, pxT = p_t & 7;
    int gp = (ty * 8 + pyT) * WW + tx * 8 + pxT;
    uint4 ar = *(const uint4*)&att_bf[((size_t)b * HWP + gp) * 16 + q * 4];
    bf16x8 afrag = __builtin_bit_cast(bf16x8, ar);

    uint4 z4 = {0u, 0u, 0u, 0u};

    // ========== PASS A: h(c1) on 12x12 halo via MFMA ==========
    {
        int rgA[3]; int nA;
        if (wy == 0) { rgA[0] = 0; rgA[1] = 4; rgA[2] = 8; nA = 3; }
        else         { rgA[0] = wy; rgA[1] = wy + 4; rgA[2] = 0; nA = 2; }
        #pragma unroll 1
        for (int rr = 0; rr < nA; ++rr) {
            int rg = rgA[rr];
            int hp = rg * 16 + i16;
            int hy = hp / 12, hx = hp - hy * 12;
            int gy = ty * 8 - 2 + hy, gx = tx * 8 - 2 + hx;
            bool inb = ((unsigned)gy < (unsigned)HH) & ((unsigned)gx < (unsigned)WW);
            const uint4* xp4 = (const uint4*)&xpb[(size_t)(inb ? gy * WW + gx : 0) * 24];
            uint4 ra = inb ? xp4[q] : z4;
            uint4 rb = (inb && q < 2) ? xp4[4 + q] : z4;
            bf16x8 a0 = __builtin_bit_cast(bf16x8, ra);
            bf16x8 a1 = __builtin_bit_cast(bf16x8, rb);
            int rowb = rg * 16 + 4 * q;
            #pragma unroll
            for (int nt = 0; nt < 6; ++nt) {
                bf16x8 b0 = __builtin_bit_cast(bf16x8, Bpw[(size_t)((6 + nt) << 6) + lane]);
                bf16x8 b1 = __builtin_bit_cast(bf16x8, Bpw[(size_t)((18 + nt) << 6) + lane]);
                f32x4 z = {0.f, 0.f, 0.f, 0.f};
                f32x4 c = __builtin_amdgcn_mfma_f32_16x16x32_bf16(a1, b1, z, 0, 0, 0);
                c = __builtin_amdgcn_mfma_f32_16x16x32_bf16(a0, b0, c, 0, 0, 0);
                #pragma unroll
                for (int r = 0; r < 4; ++r)
                    st_bf_hi(&hsw[(rowb + r) * 100 + nt * 16 + i16], c[r]);
            }
        }
    }
    __syncthreads();

    // ---- depthwise c1 -> uf on 10x10 halo (us2p) ----
    #pragma unroll 1
    for (int ci = 0; ci < 3; ++ci) {
        int cq = wy * 3 + ci;
        const float* w9 = c1w2 + cq * 8 * 9;          // wave-uniform -> s_loads
        #pragma unroll 1
        for (int sub = 0; sub < 2; ++sub) {
            int hp2 = sub * 64 + lane;
            if (hp2 < 100) {
                int py2 = hp2 / 10, px2 = hp2 - py2 * 10;
                float acc[8];
                #pragma unroll
                for (int c = 0; c < 8; ++c) acc[c] = 0.f;
                #pragma unroll
                for (int di = 0; di < 3; ++di)
                  #pragma unroll
                  for (int dj = 0; dj < 3; ++dj) {
                      int row = (py2 + di) * 12 + px2 + dj;
                      uint2 v0 = *(const uint2*)&hsw[row * 100 + cq * 8];
                      uint2 v1 = *(const uint2*)&hsw[row * 100 + cq * 8 + 4];
                      unsigned pp[4] = {v0.x, v0.y, v1.x, v1.y};
                      #pragma unroll
                      for (int c2 = 0; c2 < 4; ++c2) {
                          acc[2*c2]   += w9[(2*c2) * 9 + di * 3 + dj]   * bfpair_lo(pp[c2]);
                          acc[2*c2+1] += w9[(2*c2+1) * 9 + di * 3 + dj] * bfpair_hi(pp[c2]);
                      }
                  }
                uint2 o0, o1;
                o0.x = pack2bf(acc[0], acc[1]);
                o0.y = pack2bf(acc[2], acc[3]);
                o1.x = pack2bf(acc[4], acc[5]);
                o1.y = pack2bf(acc[6], acc[7]);
                *(uint2*)&us2p[hp2 * 100 + cq * 8]     = o0;
                *(uint2*)&us2p[hp2 * 100 + cq * 8 + 4] = o1;
            }
        }
    }
    __syncthreads();

    // ========== PASS B: h(dw) on 10x10 halo via MFMA ==========
    {
        int rgB[2]; rgB[0] = wy; rgB[1] = wy + 4;
        int nB = (wy < 3) ? 2 : 1;
        #pragma unroll 1
        for (int rr = 0; rr < nB; ++rr) {
            int rg = rgB[rr];
            int hp = rg * 16 + i16;
            bool okp = hp < 100;
            int hy = hp / 10, hx = hp - hy * 10;
            int gy = ty * 8 - 1 + hy, gx = tx * 8 - 1 + hx;
            bool inb = okp & ((unsigned)gy < (unsigned)HH) & ((unsigned)gx < (unsigned)WW);
            const uint4* xp4 = (const uint4*)&xpb[(size_t)(inb ? gy * WW + gx : 0) * 24];
            uint4 ra = inb ? xp4[q] : z4;
            uint4 rb = (inb && q < 2) ? xp4[4 + q] : z4;
            bf16x8 a0 = __builtin_bit_cast(bf16x8, ra);
            bf16x8 a1 = __builtin_bit_cast(bf16x8, rb);
            int rowb = rg * 16 + 4 * q;
            #pragma unroll
            for (int nt = 0; nt < 6; ++nt) {
                bf16x8 b0 = __builtin_bit_cast(bf16x8, Bpw[(size_t)(nt << 6) + lane]);
                bf16x8 b1 = __builtin_bit_cast(bf16x8, Bpw[(size_t)((12 + nt) << 6) + lane]);
                f32x4 z = {0.f, 0.f, 0.f, 0.f};
                f32x4 c = __builtin_amdgcn_mfma_f32_16x16x32_bf16(a1, b1, z, 0, 0, 0);
                c = __builtin_amdgcn_mfma_f32_16x16x32_bf16(a0, b0, c, 0, 0, 0);
                #pragma unroll
                for (int r = 0; r < 4; ++r)
                    st_bf_hi(&hsw[(rowb + r) * 100 + nt * 16 + i16], c[r]);
            }
        }
    }
    __syncthreads();

    // ---- depthwise dw -> gelu(x1) for OWN pixel, channels q*24..q*24+23 (registers) ----
    f32x2 greg[12];
    {
        int base = q * 24;
        #pragma unroll
        for (int cc = 0; cc < 12; ++cc) {
            int c0 = base + 2 * cc;
            f32x2 acc = {0.f, 0.f};
            #pragma unroll
            for (int di = 0; di < 3; ++di)
              #pragma unroll
              for (int dj = 0; dj < 3; ++dj) {
                  unsigned pr = *(const unsigned*)&hsw[((pyT + di) * 10 + pxT + dj) * 100 + c0];
                  f32x2 hv = {bfpair_lo(pr), bfpair_hi(pr)};
                  f32x2 wv = *(const f32x2*)&wlds[(di * 3 + dj) * 96 + c0];
                  acc += wv * hv;
              }
            greg[cc].x = gelu(acc.x);
            greg[cc].y = gelu(acc.y);
        }
    }
    __syncthreads();   // all waves done reading h_dw -> Wc may overwrite hsw

    // ========== KBA chunk loop (fully unrolled; gelu in registers) ==========
    unsigned* cmb = comb_bf + ((size_t)b * HWP + gp) * 48 + q * 12;
    int hpC = (pyT + 1) * 10 + pxT + 1;

    #pragma unroll
    for (int chunk = 0; chunk < 12; ++chunk) {
        #pragma unroll
        for (int nt = 0; nt < 10; ++nt) {
            bf16x8 bfrag = __builtin_bit_cast(bf16x8, Bpk[(size_t)((chunk * 10 + nt) << 6) + lane]);
            f32x4 z = {0.f, 0.f, 0.f, 0.f};
            f32x4 cfr = __builtin_amdgcn_mfma_f32_16x16x32_bf16(afrag, bfrag, z, 0, 0, 0);
            #pragma unroll
            for (int r = 0; r < 4; ++r)
                st_bf_hi(&Wc[wy][4 * q + r][nt * 16 + i16], cfr[r]);
        }
        // same-wave LDS RAW: lgkmcnt handles ordering, no barrier
        int c0 = q * 24 + 2 * chunk;
        float u[18];
        #pragma unroll
        for (int i = 0; i < 3; ++i)
          #pragma unroll
          for (int j = 0; j < 3; ++j) {
              unsigned pr = *(const unsigned*)&us2p[((pyT + i) * 10 + pxT + j) * 100 + c0];
              u[i * 3 + j]     = bfpair_lo(pr);
              u[9 + i * 3 + j] = bfpair_hi(pr);
          }
        uint4 wr[5];
        const unsigned short* wrow = &Wc[wy][i16][q * 40];
        #pragma unroll
        for (int t5 = 0; t5 < 5; ++t5) wr[t5] = *(const uint4*)&wrow[t5 * 8];
        const unsigned short* wu = (const unsigned short*)wr;
        float acc0 = bf2f(wu[18]);
        float acc1 = bf2f(wu[38]);
        #pragma unroll
        for (int m = 0; m < 18; ++m) {
            acc0 += bf2f(wu[m])      * u[m];
            acc1 += bf2f(wu[20 + m]) * u[m];
        }
        unsigned sp = *(const unsigned*)&us2p[hpC * 100 + c0];
        float x20 = acc0 + bfpair_lo(sp);     // ga1 pre-folded into Bpk
        float x21 = acc1 + bfpair_hi(sp);
        float cv0 = greg[chunk].x * x20;
        float cv1 = greg[chunk].y * x21;
        cmb[chunk] = pack2bf(cv0, cv1);
        float r0 = cv0, r1 = cv1;
        #pragma unroll
        for (int s = 1; s < 16; s <<= 1) {
            r0 += __shfl_xor(r0, s, 64);
            r1 += __shfl_xor(r1, s, 64);
        }
        if (i16 == 0) {
            atomicAdd(&pooled_s[c0], r0);
            atomicAdd(&pooled_s[c0 + 1], r1);
        }
    }
    __syncthreads();
    if (tid < 96) atomicAdd(&pooled[b * HIDC + tid], pooled_s[tid]);
}

// ---------------- K3: sv (fused) + out = proj1x1( comb * sv ) ----------------
__global__ __launch_bounds__(256) void k_final(
    const unsigned* __restrict__ comb_bf, const float* __restrict__ pooled,
    const float* __restrict__ scaw, const float* __restrict__ scab,
    const float* __restrict__ projw, float* __restrict__ out)
{
    __shared__ float svs[96];
    __shared__ float cs[96][66];
    int tid = threadIdx.x;
    int blk = blockIdx.x;
    int p0 = blk * 64;
    int b = p0 >> 14;
    if (tid < 96) {
        float dot = 0.f;
        const float* pr = pooled + b * 96;
        const float* wr = scaw + tid * 96;
        #pragma unroll 4
        for (int k = 0; k < 96; ++k) dot += wr[k] * pr[k];
        svs[tid] = scab[tid] + dot * (1.0f / (float)HWP);
    }
    __syncthreads();
    for (int idx = tid; idx < 64 * 12; idx += 256) {
        int px = idx / 12, cq = idx - px * 12;
        uint4 v = *(const uint4*)&comb_bf[(size_t)(p0 + px) * 48 + cq * 4];
        int k0 = cq * 8;
        unsigned pp[4] = {v.x, v.y, v.z, v.w};
        #pragma unroll
        for (int j = 0; j < 4; ++j) {
            cs[k0 + 2*j][px]     = bfpair_lo(pp[j]) * svs[k0 + 2*j];
            cs[k0 + 2*j + 1][px] = bfpair_hi(pp[j]) * svs[k0 + 2*j + 1];
        }
    }
    __syncthreads();
    int l = tid & 63, w = tid >> 6;
    int o0 = w * 12;
    float acc[12];
    #pragma unroll
    for (int o = 0; o < 12; ++o) acc[o] = 0.f;
    #pragma unroll 4
    for (int k = 0; k < 96; ++k) {
        float v = cs[k][l];
        #pragma unroll
        for (int o = 0; o < 12; ++o)
            acc[o] += projw[(o0 + o) * 96 + k] * v;      // wave-uniform -> s_loads
    }
    float* ob = out + (size_t)b * DIMC * HWP + (p0 & 16383) + l;
    #pragma unroll
    for (int o = 0; o < 12; ++o)
        ob[(o0 + o) * HWP] = acc[o];
}

extern "C" void kernel_launch(void* const* d_in, const int* in_sizes, int n_in,
                              void* d_out, int out_size, void* d_ws, size_t ws_size,
                              hipStream_t stream)
{
    const float* x     = (const float*)d_in[0];
    const float* dw1w  = (const float*)d_in[1];
    const float* dw2w  = (const float*)d_in[2];
    const float* projw = (const float*)d_in[3];
    const float* scaw  = (const float*)d_in[4];
    const float* scab  = (const float*)d_in[5];
    const float* c1w1  = (const float*)d_in[6];
    const float* c1w2  = (const float*)d_in[7];
    const float* kbaw  = (const float*)d_in[8];
    const float* kbab  = (const float*)d_in[9];
    const float* c2w1  = (const float*)d_in[10];
    const float* c2b1  = (const float*)d_in[11];
    const float* c2w2  = (const float*)d_in[12];
    const float* c2b2  = (const float*)d_in[13];
    const float* c211w = (const float*)d_in[14];
    const float* c211b = (const float*)d_in[15];
    const float* attg  = (const float*)d_in[16];
    const float* ga1   = (const float*)d_in[17];

    unsigned* x_p     = (unsigned*)d_ws;                           // 1,572,864 dw
    unsigned* att_bf  = x_p + (size_t)BB * HWP * 24;               // 1,048,576 dw
    unsigned* comb_bf = att_bf + (size_t)BB * HWP * 16;            // 3,145,728 dw
    float* pooled     = (float*)(comb_bf + (size_t)BB * HWP * 48); // 384 f
    unsigned short* Bpk = (unsigned short*)(pooled + BB * HIDC);   // 61,440 ush
    unsigned short* Bpw = Bpk + 120 * 512;                         // 12,288 ush

    k_prep <<<544,  256, 0, stream>>>(x, kbaw, kbab, dw1w, c1w1, ga1, Bpk, Bpw, x_p, pooled);
    k_att  <<<512,  256, 0, stream>>>(x_p, c2w1, c2b1, c2w2, c2b2, c211w, c211b, attg, att_bf);
    k_mff  <<<1024, dim3(64,4,1), 0, stream>>>(x_p, att_bf, (const uint4*)Bpw, (const uint4*)Bpk,
                                               c1w2, dw2w, comb_bf, pooled);
    k_final<<<1024, 256, 0, stream>>>(comb_bf, pooled, scaw, scab, projw, (float*)d_out);
}

// Round 9
// 207.214 us; speedup vs baseline: 4.7770x; 1.1871x over previous
//
#include <hip/hip_runtime.h>
#include <math.h>

#define BB 4
#define HH 128
#define WW 128
#define HWP (HH*WW)
#define DIMC 48
#define HIDC 96
#define NSETC 32

typedef __attribute__((ext_vector_type(8))) short bf16x8;
typedef __attribute__((ext_vector_type(4))) float f32x4;
typedef __attribute__((ext_vector_type(2))) float f32x2;

static __device__ __forceinline__ unsigned short f2bf(float f) {   // RNE (pack path, cold)
    union { float f; unsigned u; } v; v.f = f;
    unsigned r = (v.u + 0x7FFFu + ((v.u >> 16) & 1u)) >> 16;
    return (unsigned short)r;
}
static __device__ __forceinline__ unsigned rnd_bf(float f) {       // +0x8000 round-half-up
    union { float f; unsigned u; } v; v.f = f;
    return v.u + 0x8000u;
}
static __device__ __forceinline__ unsigned pack2bf(float lo, float hi) {
    return __builtin_amdgcn_perm(rnd_bf(hi), rnd_bf(lo), 0x07060302u);
}
static __device__ __forceinline__ void st_bf_hi(unsigned short* p, float f) {
    *p = (unsigned short)(rnd_bf(f) >> 16);
}
static __device__ __forceinline__ float bf2f(unsigned short u) {
    union { unsigned u; float f; } v; v.u = ((unsigned)u) << 16;
    return v.f;
}
static __device__ __forceinline__ float bfpair_lo(unsigned pr) {
    union { unsigned u; float f; } v; v.u = pr << 16; return v.f;
}
static __device__ __forceinline__ float bfpair_hi(unsigned pr) {
    union { unsigned u; float f; } v; v.u = pr & 0xffff0000u; return v.f;
}
static __device__ __forceinline__ float gelu(float x) {
    return 0.5f * x * (1.0f + erff(x * 0.70710678118654752f));
}

// ---------------- K0: weight pack (permuted A-operand layouts) + x transpose ----------------
// blocks [0,300): pack ; blocks [300,556): xpose (256 px each); xblk 0 zeroes pooled.
// BpkA: KBA weights as MFMA *A* operand, rows permuted so lane(q,i16) C-regs land on
//       cols 40q+4nt+r (its own epilogue cols). ga1 folded.
// Aps/Ag: att skip(K=48) / gate(K=13, biases in k=12 slot) A-operands, rows permuted so
//       C rows land on n = 8q+4nt2+r (each lane's own afrag slice).
__global__ __launch_bounds__(256) void k_prep(
    const float* __restrict__ x,
    const float* __restrict__ kbaw, const float* __restrict__ kbab,
    const float* __restrict__ dw1w, const float* __restrict__ c1w1,
    const float* __restrict__ ga1,  const float* __restrict__ c211w,
    const float* __restrict__ c2w2, const float* __restrict__ c2b2,
    const float* __restrict__ c211b, const float* __restrict__ attg,
    unsigned short* __restrict__ Bpk, unsigned short* __restrict__ Bpw,
    unsigned short* __restrict__ Aps, unsigned short* __restrict__ Ag,
    unsigned* __restrict__ x_p, float* __restrict__ pooled)
{
    __shared__ unsigned ts[256 * 26];
    int blk = blockIdx.x, tid = threadIdx.x;
    if (blk < 300) {
        int t = blk * 256 + tid;
        if (t < 61440) {                         // BpkA
            int j = t & 7, lane = (t >> 3) & 63, tile = t >> 9;
            int chunk = tile / 10, nt = tile - chunk * 10;
            int m = lane & 15, qn = lane >> 4;
            int lc = 4 * nt + (m & 3);           // local col within this q's 40-block
            int o = lc / 20, tt = lc % 20;
            int c = (m >> 2) * 24 + 2 * chunk + o;
            int n = qn * 8 + j;
            float v = 0.f;
            if (tt < 18)       v = kbaw[n * 1728 + (c >> 1) * 36 + (c & 1) * 18 + tt] * ga1[c];
            else if (tt == 18) v = kbab[n * 96 + c] * ga1[c];
            Bpk[t] = f2bf(v);
        } else if (t < 73728) {                  // Bpw (B operand, unchanged)
            int u = t - 61440;
            int s = u / 6144;
            int rem = u % 6144;
            int nt = rem >> 9;
            int lane = (rem >> 3) & 63, j = rem & 7;
            int k = s * 32 + ((lane >> 4) << 3) + j;
            int col = (nt << 4) + (lane & 15);
            float v = 0.f;
            if (k < 48) v = (col < 96) ? dw1w[col * 48 + k] : c1w1[(col - 96) * 48 + k];
            Bpw[u] = f2bf(v);
        } else if (t < 75776) {                  // Aps (skip 1x1 A-operand)
            int u = t - 73728;
            int j = u & 7, lane = (u >> 3) & 63, tile = u >> 9;   // 0..3 = kt*2+nt2
            int kt = tile >> 1, nt2 = tile & 1;
            int m = lane & 15, qn = lane >> 4;
            int n = 8 * (m >> 2) + 4 * nt2 + (m & 3);
            int k = kt * 32 + qn * 8 + j;
            Aps[u] = f2bf(k < 48 ? c211w[n * 48 + k] : 0.f);
        } else if (t < 76800) {                  // Ag (gate 1x1 A-operand, biases at k=12)
            int u = t - 75776;
            int j = u & 7, lane = (u >> 3) & 63, nt2 = u >> 9;    // 0..1
            int m = lane & 15, qn = lane >> 4;
            int n = 8 * (m >> 2) + 4 * nt2 + (m & 3);
            int k = qn * 8 + j;
            float v = 0.f;
            if (k < 12)       v = c2w2[n * 12 + k] * attg[n];
            else if (k == 12) v = c2b2[n] * attg[n] + c211b[n];
            Ag[u] = f2bf(v);
        }
    } else {
        int xblk = blk - 300;
        if (xblk == 0) {
            for (int i = tid; i < BB * HIDC; i += 256) pooled[i] = 0.f;
        }
        int b = xblk >> 6;
        int p0 = (xblk & 63) << 8;
        const float* xb = x + (size_t)b * DIMC * HWP + p0;
        #pragma unroll
        for (int c2 = 0; c2 < 24; ++c2) {
            float lo = xb[(2 * c2) * HWP + tid];
            float hi = xb[(2 * c2 + 1) * HWP + tid];
            ts[tid * 26 + c2] = pack2bf(lo, hi);
        }
        __syncthreads();
        unsigned* dst = x_p + ((size_t)b * HWP + p0) * 24;
        for (int idx = tid; idx < 256 * 24; idx += 256) {
            int px = idx / 24, j2 = idx - px * 24;
            dst[px * 24 + j2] = ts[px * 26 + j2];
        }
    }
}

// ---------------- K1 (mega-fused): att + 1x1 MFMA + depthwise + KBA -> comb(bf16) ----------------
// 1024 blocks, dim3(64,4); 2 blocks/CU (LDS ~69.4 KB). KBA epilogue weights stay in VGPRs
// (permuted-A MFMA) -- no Wc LDS round-trip.
__global__ __launch_bounds__(256, 2) void k_mff(
    const unsigned* __restrict__ x_p,
    const uint4* __restrict__ BpkA, const uint4* __restrict__ Bpw,
    const uint4* __restrict__ Aps,  const uint4* __restrict__ Ag,
    const float* __restrict__ c1w2, const float* __restrict__ dw2w,
    const float* __restrict__ c2w1, const float* __restrict__ c2b1,
    unsigned* __restrict__ comb_bf, float* __restrict__ pooled)
{
    __shared__ __attribute__((aligned(16))) unsigned xs[144 * 26];          // x halo 12x12, bf16 pairs (15.0 KB)
    __shared__ __attribute__((aligned(16))) unsigned short hsw[144 * 100];  // h tiles ; aliased att_t (28.8 KB)
    __shared__ unsigned short us2p[100 * 100];                              // uf halo (20.0 KB)
    __shared__ float wls[864 + 432 + 24];                                   // dw2w | c2w1-relayout | c2b1 (5.3 KB)
    __shared__ float pooled_s[96];

    int lane = threadIdx.x, wy = threadIdx.y;
    int tid = wy * 64 + lane;
    int blk = blockIdx.x;
    int b = blk >> 8, ty = (blk >> 4) & 15, tx = blk & 15;
    int q = lane >> 4, i16 = lane & 15;

    float* wats  = wls + 864;    // [g][tap][2]
    float* c2b1s = wls + 864 + 432;
    float* att_tf = (float*)hsw; // [px(64)][26] floats, lives before PASS A

    // ---- stage: xs / weight tables / pooled_s ----
    if (tid < 96) pooled_s[tid] = 0.f;
    for (int idx = tid; idx < 864; idx += 256) {
        int t5 = idx / 96, c = idx - t5 * 96;
        wls[idx] = dw2w[c * 9 + t5];
    }
    for (int idx = tid; idx < 216; idx += 256) {
        int g = idx / 9, tap = idx - g * 9;
        wats[idx * 2]     = c2w1[g * 18 + tap];
        wats[idx * 2 + 1] = c2w1[g * 18 + 9 + tap];
    }
    if (tid < 24) c2b1s[tid] = c2b1[tid];
    for (int idx = tid; idx < 144 * 12; idx += 256) {
        int pos = idx / 12, jp = idx - pos * 12;
        int gy = ty * 8 - 2 + pos / 12, gx = tx * 8 - 2 + pos % 12;
        uint2 v = {0u, 0u};
        if (((unsigned)gy < (unsigned)HH) & ((unsigned)gx < (unsigned)WW))
            v = *(const uint2*)&x_p[((size_t)b * HWP + gy * WW + gx) * 24 + jp * 2];
        *(uint2*)&xs[pos * 26 + jp * 2] = v;
    }
    __syncthreads();

    int p_t = wy * 16 + i16;
    int pyT = p_t >> 3, pxT = p_t & 7;
    int gp = (ty * 8 + pyT) * WW + tx * 8 + pxT;
    uint4 z4 = {0u, 0u, 0u, 0u};

    // ---- att: grouped conv t (4 threads/pixel, 6 groups each) ----
    #pragma unroll
    for (int ci = 0; ci < 6; ++ci) {
        int g = q * 6 + ci;
        float acc = c2b1s[g];
        #pragma unroll
        for (int di = 0; di < 3; ++di)
          #pragma unroll
          for (int dj = 0; dj < 3; ++dj) {
              unsigned pr = xs[((pyT + 1 + di) * 12 + pxT + 1 + dj) * 26 + g];
              f32x2 w2 = *(const f32x2*)&wats[(g * 9 + di * 3 + dj) * 2];
              acc += w2.x * bfpair_lo(pr) + w2.y * bfpair_hi(pr);
          }
        att_tf[p_t * 26 + g] = acc;
    }
    __syncthreads();

    // ---- att: gate + skip via permuted-A MFMA -> afrag in registers ----
    bf16x8 afrag;
    {
        int p26 = p_t * 26;
        unsigned tgd[4];
        #pragma unroll
        for (int i2 = 0; i2 < 4; ++i2) {
            int k0 = q * 8 + 2 * i2;
            int k1 = k0 + 1;
            float v0 = (k0 < 12) ? att_tf[p26 + k0] * att_tf[p26 + 12 + k0] : (k0 == 12 ? 1.f : 0.f);
            float v1 = (k1 < 12) ? att_tf[p26 + k1] * att_tf[p26 + 12 + k1] : (k1 == 12 ? 1.f : 0.f);
            tgd[i2] = pack2bf(v0, v1);
        }
        uint4 tgr = {tgd[0], tgd[1], tgd[2], tgd[3]};
        bf16x8 btg = __builtin_bit_cast(bf16x8, tgr);

        int cen = (pyT + 2) * 12 + (pxT + 2);
        uint2 xa = *(const uint2*)&xs[cen * 26 + q * 4];
        uint2 xb2 = *(const uint2*)&xs[cen * 26 + q * 4 + 2];
        uint4 bx0r = {xa.x, xa.y, xb2.x, xb2.y};
        uint4 bx1r = z4;                // MUST be zeroed for q>=2: xs entries 24+ are
        if (q < 2) {                    // unwritten garbage; 0-weight x NaN = NaN (round-8 bug)
            uint2 xc = *(const uint2*)&xs[cen * 26 + 16 + q * 4];
            uint2 xd = *(const uint2*)&xs[cen * 26 + 16 + q * 4 + 2];
            bx1r.x = xc.x; bx1r.y = xc.y; bx1r.z = xd.x; bx1r.w = xd.y;
        }
        bf16x8 bx0 = __builtin_bit_cast(bf16x8, bx0r);
        bf16x8 bx1 = __builtin_bit_cast(bf16x8, bx1r);

        float attv[8];
        #pragma unroll
        for (int nt2 = 0; nt2 < 2; ++nt2) {
            bf16x8 ag  = __builtin_bit_cast(bf16x8, Ag[nt2 * 64 + lane]);
            bf16x8 as0 = __builtin_bit_cast(bf16x8, Aps[nt2 * 64 + lane]);
            bf16x8 as1 = __builtin_bit_cast(bf16x8, Aps[(2 + nt2) * 64 + lane]);
            f32x4 z = {0.f, 0.f, 0.f, 0.f};
            f32x4 c = __builtin_amdgcn_mfma_f32_16x16x32_bf16(ag, btg, z, 0, 0, 0);
            c = __builtin_amdgcn_mfma_f32_16x16x32_bf16(as1, bx1, c, 0, 0, 0);
            c = __builtin_amdgcn_mfma_f32_16x16x32_bf16(as0, bx0, c, 0, 0, 0);
            #pragma unroll
            for (int r = 0; r < 4; ++r) attv[nt2 * 4 + r] = c[r];
        }
        uint4 au = {pack2bf(attv[0], attv[1]), pack2bf(attv[2], attv[3]),
                    pack2bf(attv[4], attv[5]), pack2bf(attv[6], attv[7])};
        afrag = __builtin_bit_cast(bf16x8, au);
    }
    __syncthreads();   // att_tf dead -> hsw free for PASS A

    // ========== PASS A: h(c1) on 12x12 halo via MFMA (frags from xs) ==========
    {
        int rgA[3]; int nA;
        if (wy == 0) { rgA[0] = 0; rgA[1] = 4; rgA[2] = 8; nA = 3; }
        else         { rgA[0] = wy; rgA[1] = wy + 4; rgA[2] = 0; nA = 2; }
        #pragma unroll 1
        for (int rr = 0; rr < nA; ++rr) {
            int rg = rgA[rr];
            int hp = rg * 16 + i16;
            uint2 xa = *(const uint2*)&xs[hp * 26 + q * 4];
            uint2 xb2 = *(const uint2*)&xs[hp * 26 + q * 4 + 2];
            uint4 a0r = {xa.x, xa.y, xb2.x, xb2.y};
            uint4 a1r = z4;
            if (q < 2) {
                uint2 xc = *(const uint2*)&xs[hp * 26 + 16 + q * 4];
                uint2 xd = *(const uint2*)&xs[hp * 26 + 16 + q * 4 + 2];
                a1r.x = xc.x; a1r.y = xc.y; a1r.z = xd.x; a1r.w = xd.y;
            }
            bf16x8 a0 = __builtin_bit_cast(bf16x8, a0r);
            bf16x8 a1 = __builtin_bit_cast(bf16x8, a1r);
            int rowb = rg * 16 + 4 * q;
            #pragma unroll
            for (int nt = 0; nt < 6; ++nt) {
                bf16x8 b0 = __builtin_bit_cast(bf16x8, Bpw[(size_t)((6 + nt) << 6) + lane]);
                bf16x8 b1 = __builtin_bit_cast(bf16x8, Bpw[(size_t)((18 + nt) << 6) + lane]);
                f32x4 z = {0.f, 0.f, 0.f, 0.f};
                f32x4 c = __builtin_amdgcn_mfma_f32_16x16x32_bf16(a1, b1, z, 0, 0, 0);
                c = __builtin_amdgcn_mfma_f32_16x16x32_bf16(a0, b0, c, 0, 0, 0);
                #pragma unroll
                for (int r = 0; r < 4; ++r)
                    st_bf_hi(&hsw[(rowb + r) * 100 + nt * 16 + i16], c[r]);
            }
        }
    }
    __syncthreads();

    // ---- depthwise c1 -> uf on 10x10 halo (us2p) ----
    #pragma unroll 1
    for (int ci = 0; ci < 3; ++ci) {
        int cq = wy * 3 + ci;
        const float* w9 = c1w2 + cq * 8 * 9;          // wave-uniform -> s_loads
        #pragma unroll 1
        for (int sub = 0; sub < 2; ++sub) {
            int hp2 = sub * 64 + lane;
            if (hp2 < 100) {
                int py2 = hp2 / 10, px2 = hp2 - py2 * 10;
                float acc[8];
                #pragma unroll
                for (int c = 0; c < 8; ++c) acc[c] = 0.f;
                #pragma unroll
                for (int di = 0; di < 3; ++di)
                  #pragma unroll
                  for (int dj = 0; dj < 3; ++dj) {
                      int row = (py2 + di) * 12 + px2 + dj;
                      uint2 v0 = *(const uint2*)&hsw[row * 100 + cq * 8];
                      uint2 v1 = *(const uint2*)&hsw[row * 100 + cq * 8 + 4];
                      unsigned pp[4] = {v0.x, v0.y, v1.x, v1.y};
                      #pragma unroll
                      for (int c2 = 0; c2 < 4; ++c2) {
                          acc[2*c2]   += w9[(2*c2) * 9 + di * 3 + dj]   * bfpair_lo(pp[c2]);
                          acc[2*c2+1] += w9[(2*c2+1) * 9 + di * 3 + dj] * bfpair_hi(pp[c2]);
                      }
                  }
                uint2 o0, o1;
                o0.x = pack2bf(acc[0], acc[1]);
                o0.y = pack2bf(acc[2], acc[3]);
                o1.x = pack2bf(acc[4], acc[5]);
                o1.y = pack2bf(acc[6], acc[7]);
                *(uint2*)&us2p[hp2 * 100 + cq * 8]     = o0;
                *(uint2*)&us2p[hp2 * 100 + cq * 8 + 4] = o1;
            }
        }
    }
    __syncthreads();

    // ========== PASS B: h(dw) on 10x10 halo via MFMA ==========
    {
        int rgB[2]; rgB[0] = wy; rgB[1] = wy + 4;
        int nB = (wy < 3) ? 2 : 1;
        #pragma unroll 1
        for (int rr = 0; rr < nB; ++rr) {
            int rg = rgB[rr];
            int hp = rg * 16 + i16;
            bool okp = hp < 100;
            int hy = hp / 10, hx = hp - hy * 10;
            int pos = okp ? ((hy + 1) * 12 + hx + 1) : 0;
            uint2 xa = *(const uint2*)&xs[pos * 26 + q * 4];
            uint2 xb2 = *(const uint2*)&xs[pos * 26 + q * 4 + 2];
            uint4 a0r = {xa.x, xa.y, xb2.x, xb2.y};
            uint4 a1r = z4;
            if (q < 2) {
                uint2 xc = *(const uint2*)&xs[pos * 26 + 16 + q * 4];
                uint2 xd = *(const uint2*)&xs[pos * 26 + 16 + q * 4 + 2];
                a1r.x = xc.x; a1r.y = xc.y; a1r.z = xd.x; a1r.w = xd.y;
            }
            bf16x8 a0 = __builtin_bit_cast(bf16x8, a0r);
            bf16x8 a1 = __builtin_bit_cast(bf16x8, a1r);
            int rowb = rg * 16 + 4 * q;
            #pragma unroll
            for (int nt = 0; nt < 6; ++nt) {
                bf16x8 b0 = __builtin_bit_cast(bf16x8, Bpw[(size_t)(nt << 6) + lane]);
                bf16x8 b1 = __builtin_bit_cast(bf16x8, Bpw[(size_t)((12 + nt) << 6) + lane]);
                f32x4 z = {0.f, 0.f, 0.f, 0.f};
                f32x4 c = __builtin_amdgcn_mfma_f32_16x16x32_bf16(a1, b1, z, 0, 0, 0);
                c = __builtin_amdgcn_mfma_f32_16x16x32_bf16(a0, b0, c, 0, 0, 0);
                #pragma unroll
                for (int r = 0; r < 4; ++r)
                    st_bf_hi(&hsw[(rowb + r) * 100 + nt * 16 + i16], c[r]);  // rows>=100 harmless
            }
        }
    }
    __syncthreads();

    // ---- depthwise dw -> gelu(x1) for OWN pixel, channels q*24..q*24+23 (registers) ----
    f32x2 greg[12];
    {
        int base = q * 24;
        #pragma unroll
        for (int cc = 0; cc < 12; ++cc) {
            int c0 = base + 2 * cc;
            f32x2 acc = {0.f, 0.f};
            #pragma unroll
            for (int di = 0; di < 3; ++di)
              #pragma unroll
              for (int dj = 0; dj < 3; ++dj) {
                  unsigned pr = *(const unsigned*)&hsw[((pyT + di) * 10 + pxT + dj) * 100 + c0];
                  f32x2 hv = {bfpair_lo(pr), bfpair_hi(pr)};
                  f32x2 wv = *(const f32x2*)&wls[(di * 3 + dj) * 96 + c0];
                  acc += wv * hv;
              }
            greg[cc].x = gelu(acc.x);
            greg[cc].y = gelu(acc.y);
        }
    }
    // no barrier needed: KBA never writes hsw

    // ========== KBA: permuted-A MFMA, weights land in this thread's VGPRs ==========
    unsigned* cmb = comb_bf + ((size_t)b * HWP + gp) * 48 + q * 12;
    int hpC = (pyT + 1) * 10 + pxT + 1;

    #pragma unroll
    for (int chunk = 0; chunk < 12; ++chunk) {
        f32x4 cf[10];
        #pragma unroll
        for (int nt = 0; nt < 10; ++nt) {
            bf16x8 aW = __builtin_bit_cast(bf16x8, BpkA[(size_t)((chunk * 10 + nt) << 6) + lane]);
            f32x4 z = {0.f, 0.f, 0.f, 0.f};
            cf[nt] = __builtin_amdgcn_mfma_f32_16x16x32_bf16(aW, afrag, z, 0, 0, 0);
        }
        int c0 = q * 24 + 2 * chunk;
        float u[18];
        #pragma unroll
        for (int i = 0; i < 3; ++i)
          #pragma unroll
          for (int j = 0; j < 3; ++j) {
              unsigned pr = *(const unsigned*)&us2p[((pyT + i) * 10 + pxT + j) * 100 + c0];
              u[i * 3 + j]     = bfpair_lo(pr);
              u[9 + i * 3 + j] = bfpair_hi(pr);
          }
        float acc0 = cf[4][2];           // bias slots
        float acc1 = cf[9][2];
        #pragma unroll
        for (int m = 0; m < 16; ++m) {
            acc0 += cf[m >> 2][m & 3]       * u[m];
            acc1 += cf[5 + (m >> 2)][m & 3] * u[m];
        }
        acc0 += cf[4][0] * u[16] + cf[4][1] * u[17];
        acc1 += cf[9][0] * u[16] + cf[9][1] * u[17];

        unsigned sp = *(const unsigned*)&us2p[hpC * 100 + c0];
        float x20 = acc0 + bfpair_lo(sp);     // ga1 pre-folded into BpkA
        float x21 = acc1 + bfpair_hi(sp);
        float cv0 = greg[chunk].x * x20;
        float cv1 = greg[chunk].y * x21;
        cmb[chunk] = pack2bf(cv0, cv1);
        float r0 = cv0, r1 = cv1;
        #pragma unroll
        for (int s = 1; s < 16; s <<= 1) {
            r0 += __shfl_xor(r0, s, 64);
            r1 += __shfl_xor(r1, s, 64);
        }
        if (i16 == 0) {
            atomicAdd(&pooled_s[c0], r0);
            atomicAdd(&pooled_s[c0 + 1], r1);
        }
    }
    __syncthreads();
    if (tid < 96) atomicAdd(&pooled[b * HIDC + tid], pooled_s[tid]);
}

// ---------------- K2: sv (fused) + out = proj1x1( comb * sv ) ----------------
__global__ __launch_bounds__(256) void k_final(
    const unsigned* __restrict__ comb_bf, const float* __restrict__ pooled,
    const float* __restrict__ scaw, const float* __restrict__ scab,
    const float* __restrict__ projw, float* __restrict__ out)
{
    __shared__ float svs[96];
    __shared__ float cs[96][66];
    int tid = threadIdx.x;
    int blk = blockIdx.x;
    int p0 = blk * 64;
    int b = p0 >> 14;
    if (tid < 96) {
        float dot = 0.f;
        const float* pr = pooled + b * 96;
        const float* wr = scaw + tid * 96;
        #pragma unroll 4
        for (int k = 0; k < 96; ++k) dot += wr[k] * pr[k];
        svs[tid] = scab[tid] + dot * (1.0f / (float)HWP);
    }
    __syncthreads();
    for (int idx = tid; idx < 64 * 12; idx += 256) {
        int px = idx / 12, cq = idx - px * 12;
        uint4 v = *(const uint4*)&comb_bf[(size_t)(p0 + px) * 48 + cq * 4];
        int k0 = cq * 8;
        unsigned pp[4] = {v.x, v.y, v.z, v.w};
        #pragma unroll
        for (int j = 0; j < 4; ++j) {
            cs[k0 + 2*j][px]     = bfpair_lo(pp[j]) * svs[k0 + 2*j];
            cs[k0 + 2*j + 1][px] = bfpair_hi(pp[j]) * svs[k0 + 2*j + 1];
        }
    }
    __syncthreads();
    int l = tid & 63, w = tid >> 6;
    int o0 = w * 12;
    float acc[12];
    #pragma unroll
    for (int o = 0; o < 12; ++o) acc[o] = 0.f;
    #pragma unroll 4
    for (int k = 0; k < 96; ++k) {
        float v = cs[k][l];
        #pragma unroll
        for (int o = 0; o < 12; ++o)
            acc[o] += projw[(o0 + o) * 96 + k] * v;      // wave-uniform -> s_loads
    }
    float* ob = out + (size_t)b * DIMC * HWP + (p0 & 16383) + l;
    #pragma unroll
    for (int o = 0; o < 12; ++o)
        ob[(o0 + o) * HWP] = acc[o];
}

extern "C" void kernel_launch(void* const* d_in, const int* in_sizes, int n_in,
                              void* d_out, int out_size, void* d_ws, size_t ws_size,
                              hipStream_t stream)
{
    const float* x     = (const float*)d_in[0];
    const float* dw1w  = (const float*)d_in[1];
    const float* dw2w  = (const float*)d_in[2];
    const float* projw = (const float*)d_in[3];
    const float* scaw  = (const float*)d_in[4];
    const float* scab  = (const float*)d_in[5];
    const float* c1w1  = (const float*)d_in[6];
    const float* c1w2  = (const float*)d_in[7];
    const float* kbaw  = (const float*)d_in[8];
    const float* kbab  = (const float*)d_in[9];
    const float* c2w1  = (const float*)d_in[10];
    const float* c2b1  = (const float*)d_in[11];
    const float* c2w2  = (const float*)d_in[12];
    const float* c2b2  = (const float*)d_in[13];
    const float* c211w = (const float*)d_in[14];
    const float* c211b = (const float*)d_in[15];
    const float* attg  = (const float*)d_in[16];
    const float* ga1   = (const float*)d_in[17];

    unsigned* x_p     = (unsigned*)d_ws;                           // 1,572,864 dw
    unsigned* comb_bf = x_p + (size_t)BB * HWP * 24;               // 3,145,728 dw
    float* pooled     = (float*)(comb_bf + (size_t)BB * HWP * 48); // 384 f
    unsigned short* BpkA = (unsigned short*)(pooled + BB * HIDC);  // 61,440 ush
    unsigned short* Bpw  = BpkA + 61440;                           // 12,288 ush
    unsigned short* Aps  = Bpw + 12288;                            //  2,048 ush
    unsigned short* Ag   = Aps + 2048;                             //  1,024 ush

    k_prep <<<556,  256, 0, stream>>>(x, kbaw, kbab, dw1w, c1w1, ga1, c211w, c2w2, c2b2,
                                      c211b, attg, BpkA, Bpw, Aps, Ag, x_p, pooled);
    k_mff  <<<1024, dim3(64,4,1), 0, stream>>>(x_p, (const uint4*)BpkA, (const uint4*)Bpw,
                                               (const uint4*)Aps, (const uint4*)Ag,
                                               c1w2, dw2w, c2w1, c2b1, comb_bf, pooled);
    k_final<<<1024, 256, 0, stream>>>(comb_bf, pooled, scaw, scab, projw, (float*)d_out);
}